// Round 14
// baseline (10676.708 us; speedup 1.0000x reference)
//
#include <hip/hip_runtime.h>
#include <hip/hip_cooperative_groups.h>

namespace cg = cooperative_groups;

// Problem constants
#define N_MEL 80
#define ENC   512
#define ARNN  1024
#define PRE   256
#define ADIM  128
#define NFILT 32
#define KS    31
#define BSZ   16
#define TENC  128
#define TDEC  128

// Workspace layout (float offsets)
#define OFF_XA     0u          // [128][16][4096] precomputed x@Wih_x^T + bih + bhh
#define OFF_X      8388608u    // [128][16][256]  prenet out
#define OFF_H1     8912896u    // [128][16][256]  prenet hidden
#define OFF_DECIN  9437184u    // [128][16][80]
#define OFF_PM     9601024u    // [16][128][128]  processed memory
#define OFF_ATTNH  9863168u    // [2][16][1024]
#define OFF_DECH   9895936u    // [2][16][1024]
#define OFF_CTX    9928704u    // [2][16][512]
#define OFF_CTR    9945088u    // master@0 ctrB@32 subA@64+g*32 bcastA@576+g*32 bcastB@1088+g*32
#define STATE_FLOATS 83520     // OFF_ATTNH .. end of counter/broadcast region

typedef unsigned long long u64;
typedef float vf4 __attribute__((ext_vector_type(4)));   // TRUE vector -> VReg_128 in asm

__device__ __forceinline__ float sigmf(float x) { return 1.0f / (1.0f + __expf(-x)); }
__device__ __forceinline__ float tanhfast(float x) { return 1.0f - 2.0f / (__expf(2.0f * x) + 1.0f); }
__device__ __forceinline__ float dot4f(const float4& w, const float4& x) {
    return w.x * x.x + w.y * x.y + w.z * x.z + w.w * x.w;
}
__device__ __forceinline__ float dot4v(const float4& w, const vf4& x) {
    return w.x * x[0] + w.y * x[1] + w.z * x[2] + w.w * x[3];
}

// Coherent PIPELINED load (round 13, proven): plain global_load, sc0|sc1,
// vmcnt-only. Result invalid until VMWAIT().
__device__ __forceinline__ vf4 gload4(const float* p) {
    vf4 v;
    asm volatile("global_load_dwordx4 %0, %1, off sc0 sc1" : "=&v"(v) : "v"(p));
    return v;
}
#define VMWAIT()                                                                 \
    do {                                                                         \
        asm volatile("s_waitcnt vmcnt(0)" ::: "memory");                         \
        __builtin_amdgcn_sched_barrier(0);                                       \
    } while (0)

// coherent single-float store (compiler-tracked -> drained before barriers)
union F1U { unsigned u; float f; };
__device__ __forceinline__ void astoref(float* p, float v) {
    F1U c; c.f = v;
    __hip_atomic_store((unsigned*)p, c.u, __ATOMIC_RELAXED, __HIP_MEMORY_SCOPE_AGENT);
}
union F2U { u64 u; float f[2]; };
__device__ __forceinline__ float4 aload4(const float* p) {
    F2U a, b;
    a.u = __hip_atomic_load((const u64*)p,     __ATOMIC_RELAXED, __HIP_MEMORY_SCOPE_AGENT);
    b.u = __hip_atomic_load((const u64*)p + 1, __ATOMIC_RELAXED, __HIP_MEMORY_SCOPE_AGENT);
    return make_float4(a.f[0], a.f[1], b.f[0], b.f[1]);
}

// global poll (tid0 only; <=16 pollers per line by construction)
__device__ __forceinline__ void wait_ge(unsigned* p, unsigned tgt) {
    while (__hip_atomic_load(p, __ATOMIC_RELAXED, __HIP_MEMORY_SCOPE_AGENT) < tgt)
        __builtin_amdgcn_s_sleep(1);
    asm volatile("" ::: "memory");
}

// LDS epoch spin (direct shared-array access; no generic pointer — gfx950 isel bug)
#define LDS_SPIN(idx, tgt)                                                      \
    do {                                                                        \
        while (__hip_atomic_load(&s_done[idx], __ATOMIC_RELAXED,                \
                                 __HIP_MEMORY_SCOPE_WORKGROUP) < (tgt))         \
            __builtin_amdgcn_s_sleep(1);                                        \
        asm volatile("" ::: "memory");                                          \
    } while (0)

#define LDS_POST(idx, val)                                                      \
    __hip_atomic_store(&s_done[idx], (int)(val), __ATOMIC_RELAXED,              \
                       __HIP_MEMORY_SCOPE_WORKGROUP)

// ---------------- precompute kernels (unchanged) ----------------

__global__ void __launch_bounds__(1024) build_decin(const float* __restrict__ mels,
                                                    float* __restrict__ decin) {
    int idx = blockIdx.x * 1024 + threadIdx.x;  // 128*16*80 = 163840
    if (idx >= 128 * 16 * 80) return;
    int t = idx / 1280, r = idx % 1280;
    int b = r / 80, m = r % 80;
    decin[idx] = (t == 0) ? 0.f : mels[b * (80 * 128) + m * 128 + (t - 1)];
}

__global__ void __launch_bounds__(256) gemm_kernel(
    const float* __restrict__ A, int lda,
    const float* __restrict__ B, int ldb,
    float* __restrict__ C, int ldc,
    int M, int N, int K,
    const float* __restrict__ bias1, const float* __restrict__ bias2, int relu) {
    __shared__ float As[16][68];
    __shared__ float Bs[16][68];
    int tid = threadIdx.x;
    int tn = tid & 15, tm = tid >> 4;
    int m0 = blockIdx.y * 64, n0 = blockIdx.x * 64;
    float acc[4][4] = {};
    for (int k0 = 0; k0 < K; k0 += 16) {
        for (int idx = tid; idx < 1024; idx += 256) {
            int mm = idx >> 4, kk = idx & 15;
            int kg = k0 + kk;
            As[kk][mm] = (kg < K) ? A[(size_t)(m0 + mm) * lda + kg] : 0.f;
            Bs[kk][mm] = (kg < K) ? B[(size_t)(n0 + mm) * ldb + kg] : 0.f;
        }
        __syncthreads();
#pragma unroll
        for (int kk = 0; kk < 16; kk++) {
            float av[4], bv[4];
#pragma unroll
            for (int i = 0; i < 4; i++) { av[i] = As[kk][tm * 4 + i]; bv[i] = Bs[kk][tn * 4 + i]; }
#pragma unroll
            for (int i = 0; i < 4; i++)
#pragma unroll
                for (int j = 0; j < 4; j++) acc[i][j] += av[i] * bv[j];
        }
        __syncthreads();
    }
    for (int i = 0; i < 4; i++) {
        int m = m0 + tm * 4 + i;
        for (int j = 0; j < 4; j++) {
            int n = n0 + tn * 4 + j;
            float v = acc[i][j];
            if (bias1) v += bias1[n];
            if (bias2) v += bias2[n];
            if (relu) v = fmaxf(v, 0.f);
            C[(size_t)m * ldc + n] = v;
        }
    }
}

// ---------------- main persistent cooperative kernel ----------------

struct DecArgs {
    const float* memory;
    const int* memlen;
    const float* arnn_wih;
    const float* arnn_whh;
    const float* drnn_wih;
    const float* drnn_whh;
    const float* drnn_bih;
    const float* drnn_bhh;
    const float* query_w;
    const float* v_w;
    const float* conv_w;
    const float* dense_w;
    const float* proj_w;
    const float* proj_b;
    const float* gate_w;
    const float* gate_b;
    float* ws;
    float* out;
};

__global__ void __launch_bounds__(512, 2) decoder_main(DecArgs A) {
    cg::grid_group grid = cg::this_grid();
    const int tid = threadIdx.x;
    const int wv = tid >> 6;
    const int l = tid & 63;
    const int blk = blockIdx.x;
    const int u = wv & 3;          // unit within block's 4
    const int kq = wv >> 2;        // K-half {0,1}
    const int jj = blk * 4 + u;    // global hidden-unit id
    const int col = kq * 256 + l * 4;  // column within a 512-wide channel
    float* ws = A.ws;
    unsigned* ctrA = (unsigned*)(ws + OFF_CTR);        // master: 16 adds/step
    unsigned* ctrB = (unsigned*)(ws + OFF_CTR + 32);   // 16 adds/step
    const int grp = blk >> 4;
    unsigned* subA   = (unsigned*)(ws + OFF_CTR + 64 + grp * 32);
    unsigned* bcastA = (unsigned*)(ws + OFF_CTR + 576);   // +idx*32
    unsigned* bcastB = (unsigned*)(ws + OFF_CTR + 1088);  // +idx*32

    // LDS (~123 KB, 1 block/CU)
    __shared__ float s_pm[128 * 132];   // processed memory, padded (attn blocks)
    __shared__ float s_loc[128 * 33];
    __shared__ float s_dw[128 * 33];    // dense_w padded, persistent
    __shared__ float s_cw[1984];        // conv_w persistent (attn blocks)
    __shared__ float s_ah[1024];
    __shared__ float s_ep[512];
    __shared__ float s_part[8][64];     // LSTM partials [wave][b*4+gate]
    __shared__ float s_pp[8][64];       // dec partial (h_a,h_d channels)
    __shared__ float s_pq[128];
    __shared__ float s_aw2[128];
    __shared__ float s_awl[128];        // persistent aw state (attn blocks)
    __shared__ float s_awcl[128];       // persistent cumulative aw
    __shared__ float s_attnc[64];       // persistent attn LSTM c, [eu*16+eb]
    __shared__ float s_decc[64];        // persistent dec  LSTM c
    __shared__ float s_db[16];          // dec biases [u*4+g]
    __shared__ float s_vw[128];
    __shared__ float s_red[2];
    __shared__ int   s_done[2];         // LDS epoch mirrors of the two hops

    // ---- init: zero recurrent state + counters (ws poisoned before each call) ----
    {
        int g = blk * 512 + tid;
        if (g < STATE_FLOATS) ws[OFF_ATTNH + g] = 0.f;
    }
    if (tid < 2) s_done[tid] = 0;
    if (tid < 128) { s_awl[tid] = 0.f; s_awcl[tid] = 0.f; }
    if (tid < 64) { s_attnc[tid] = 0.f; s_decc[tid] = 0.f; }
    if (tid < 16) {
        int uu = tid >> 2, gg = tid & 3;
        s_db[tid] = A.drnn_bih[gg * 1024 + blk * 4 + uu] + A.drnn_bhh[gg * 1024 + blk * 4 + uu];
    }
    if (tid < 128) s_vw[tid] = A.v_w[tid];
    for (int idx = tid; idx < 4096; idx += 512) {
        int a = idx >> 5, f = idx & 31;
        s_dw[a * 33 + f] = A.dense_w[idx];
    }
    if (blk < 16) {
        for (int idx = tid; idx < 16384; idx += 512) {
            int tt = idx >> 7, a = idx & 127;
            s_pm[tt * 132 + a] = ws[OFF_PM + (blk * 128 + tt) * 128 + a];
        }
        for (int idx = tid; idx < 1984; idx += 512) s_cw[idx] = A.conv_w[idx];
    }
    const int ml = (blk < 16) ? A.memlen[blk] : 0;

    // ---- load persistent weight registers (once; 128 floats/thread) ----
    float4 wA[12];  // attn LSTM [ch*4+g], ch: ctx, h0, h1
    {
#pragma unroll
        for (int g = 0; g < 4; g++)
            wA[g] = *reinterpret_cast<const float4*>(
                A.arnn_wih + (size_t)(g * 1024 + jj) * 768 + 256 + col);
#pragma unroll
        for (int ch = 1; ch < 3; ch++)
#pragma unroll
            for (int g = 0; g < 4; g++)
                wA[ch * 4 + g] = *reinterpret_cast<const float4*>(
                    A.arnn_whh + (size_t)(g * 1024 + jj) * 1024 + (ch - 1) * 512 + col);
    }
    float4 wD[20];  // dec LSTM ch: ha0, ha1, ctx, hd0, hd1
    {
#pragma unroll
        for (int ch = 0; ch < 3; ch++)
#pragma unroll
            for (int g = 0; g < 4; g++)
                wD[ch * 4 + g] = *reinterpret_cast<const float4*>(
                    A.drnn_wih + (size_t)(g * 1024 + jj) * 1536 + ch * 512 + col);
#pragma unroll
        for (int ch = 3; ch < 5; ch++)
#pragma unroll
            for (int g = 0; g < 4; g++)
                wD[ch * 4 + g] = *reinterpret_cast<const float4*>(
                    A.drnn_whh + (size_t)(g * 1024 + jj) * 1024 + (ch - 3) * 512 + col);
    }
    __syncthreads();
    grid.sync();   // single cg barrier: init (incl. counters/broadcast) visible

    // packed butterfly: 4 gate-partials over 64 lanes -> lane l holds gate (l&3)
    auto reduce4 = [&](float p0, float p1, float p2, float p3) -> float {
        float a01 = (l & 1) ? p1 : p0;
        float b01 = (l & 1) ? p0 : p1;
        a01 += __shfl_xor(b01, 1);
        float a23 = (l & 1) ? p3 : p2;
        float b23 = (l & 1) ? p2 : p3;
        a23 += __shfl_xor(b23, 1);
        float k_ = (l & 2) ? a23 : a01;
        float s_ = (l & 2) ? a01 : a23;
        k_ += __shfl_xor(s_, 2);
        k_ += __shfl_xor(k_, 4);
        k_ += __shfl_xor(k_, 8);
        k_ += __shfl_xor(k_, 16);
        k_ += __shfl_xor(k_, 32);
        return k_;
    };

    // I-FOOTPRINT: group loops kept ROLLED (#pragma unroll 1); inner 4-batch
    // bodies unrolled for the load-group pipelining proven in round 13.
    auto attn_stage = [&](int t, int wpar, int rpar) {
        const float* hb = ws + OFF_ATTNH + rpar * 16384;
        const float* cb = ws + OFF_CTX + rpar * 8192;
        float xa0 = 0.f, xa1 = 0.f, xa2 = 0.f, xa3 = 0.f;
        if (tid < 64) {
            int eb = tid & 15, eu = tid >> 4;
            const float* xa = ws + OFF_XA + (size_t)(t * 16 + eb) * 4096 + (blk * 4 + eu);
            xa0 = xa[0]; xa1 = xa[1024]; xa2 = xa[2048]; xa3 = xa[3072];
        }
#pragma unroll 1
        for (int c = 0; c < 4; c++) {
            vf4 x[12];
#pragma unroll
            for (int bl = 0; bl < 4; bl++) {
                int b = c * 4 + bl;
                x[bl * 3 + 0] = gload4(cb + b * 512 + col);
                x[bl * 3 + 1] = gload4(hb + b * 1024 + col);
                x[bl * 3 + 2] = gload4(hb + b * 1024 + 512 + col);
            }
            VMWAIT();   // 12 loads in flight -> one wait per 4-batch group
#pragma unroll
            for (int bl = 0; bl < 4; bl++) {
                int b = c * 4 + bl;
                float p0 = dot4v(wA[0], x[bl*3]) + dot4v(wA[4], x[bl*3+1]) + dot4v(wA[8],  x[bl*3+2]);
                float p1 = dot4v(wA[1], x[bl*3]) + dot4v(wA[5], x[bl*3+1]) + dot4v(wA[9],  x[bl*3+2]);
                float p2 = dot4v(wA[2], x[bl*3]) + dot4v(wA[6], x[bl*3+1]) + dot4v(wA[10], x[bl*3+2]);
                float p3 = dot4v(wA[3], x[bl*3]) + dot4v(wA[7], x[bl*3+1]) + dot4v(wA[11], x[bl*3+2]);
                float r = reduce4(p0, p1, p2, p3);
                if (l < 4) s_part[wv][b * 4 + l] = r;
            }
        }
        __syncthreads();
        if (tid < 64) {
            int eu = tid >> 4, eb = tid & 15;
            float G0 = s_part[eu][eb * 4 + 0] + s_part[eu + 4][eb * 4 + 0] + xa0;
            float G1 = s_part[eu][eb * 4 + 1] + s_part[eu + 4][eb * 4 + 1] + xa1;
            float G2 = s_part[eu][eb * 4 + 2] + s_part[eu + 4][eb * 4 + 2] + xa2;
            float G3 = s_part[eu][eb * 4 + 3] + s_part[eu + 4][eb * 4 + 3] + xa3;
            float ig = sigmf(G0), fg = sigmf(G1), gg = tanhfast(G2), og = sigmf(G3);
            float c = fg * s_attnc[tid] + ig * gg;
            s_attnc[tid] = c;
            astoref(ws + OFF_ATTNH + wpar * 16384 + eb * 1024 + blk * 4 + eu, og * tanhfast(c));
        }
    };

    auto dec_partial = [&](int wpar, int rpar) {
        const float* hb = ws + OFF_ATTNH + wpar * 16384;
        const float* db = ws + OFF_DECH + rpar * 16384;
#pragma unroll 1
        for (int c = 0; c < 8; c++) {   // 2-batch groups: 8 loads in flight
            vf4 x[8];
#pragma unroll
            for (int bl = 0; bl < 2; bl++) {
                int b = c * 2 + bl;
                x[bl * 4 + 0] = gload4(hb + b * 1024 + col);
                x[bl * 4 + 1] = gload4(hb + b * 1024 + 512 + col);
                x[bl * 4 + 2] = gload4(db + b * 1024 + col);
                x[bl * 4 + 3] = gload4(db + b * 1024 + 512 + col);
            }
            VMWAIT();
#pragma unroll
            for (int bl = 0; bl < 2; bl++) {
                int b = c * 2 + bl;
                float p0 = dot4v(wD[0], x[bl*4]) + dot4v(wD[4], x[bl*4+1]) + dot4v(wD[12], x[bl*4+2]) + dot4v(wD[16], x[bl*4+3]);
                float p1 = dot4v(wD[1], x[bl*4]) + dot4v(wD[5], x[bl*4+1]) + dot4v(wD[13], x[bl*4+2]) + dot4v(wD[17], x[bl*4+3]);
                float p2 = dot4v(wD[2], x[bl*4]) + dot4v(wD[6], x[bl*4+1]) + dot4v(wD[14], x[bl*4+2]) + dot4v(wD[18], x[bl*4+3]);
                float p3 = dot4v(wD[3], x[bl*4]) + dot4v(wD[7], x[bl*4+1]) + dot4v(wD[15], x[bl*4+2]) + dot4v(wD[19], x[bl*4+3]);
                float r = reduce4(p0, p1, p2, p3);
                if (l < 4) s_pp[wv][b * 4 + l] = r;
            }
        }
    };

    auto dec_tail = [&](int wpar) {
        const float* cb = ws + OFF_CTX + wpar * 8192;
#pragma unroll 1
        for (int c = 0; c < 2; c++) {
            vf4 xc[8];
#pragma unroll
            for (int bl = 0; bl < 8; bl++) xc[bl] = gload4(cb + (c * 8 + bl) * 512 + col);
            VMWAIT();
#pragma unroll
            for (int bl = 0; bl < 8; bl++) {
                int b = c * 8 + bl;
                float p0 = dot4v(wD[8], xc[bl]);
                float p1 = dot4v(wD[9], xc[bl]);
                float p2 = dot4v(wD[10], xc[bl]);
                float p3 = dot4v(wD[11], xc[bl]);
                float r = reduce4(p0, p1, p2, p3);
                if (l < 4) s_part[wv][b * 4 + l] = r;
            }
        }
        __syncthreads();
        if (tid < 64) {
            int eu = tid >> 4, eb = tid & 15;
            float G0 = s_part[eu][eb * 4 + 0] + s_part[eu + 4][eb * 4 + 0]
                     + s_pp[eu][eb * 4 + 0] + s_pp[eu + 4][eb * 4 + 0] + s_db[eu * 4 + 0];
            float G1 = s_part[eu][eb * 4 + 1] + s_part[eu + 4][eb * 4 + 1]
                     + s_pp[eu][eb * 4 + 1] + s_pp[eu + 4][eb * 4 + 1] + s_db[eu * 4 + 1];
            float G2 = s_part[eu][eb * 4 + 2] + s_part[eu + 4][eb * 4 + 2]
                     + s_pp[eu][eb * 4 + 2] + s_pp[eu + 4][eb * 4 + 2] + s_db[eu * 4 + 2];
            float G3 = s_part[eu][eb * 4 + 3] + s_part[eu + 4][eb * 4 + 3]
                     + s_pp[eu][eb * 4 + 3] + s_pp[eu + 4][eb * 4 + 3] + s_db[eu * 4 + 3];
            float ig = sigmf(G0), fg = sigmf(G1), gg = tanhfast(G2), og = sigmf(G3);
            float c = fg * s_decc[tid] + ig * gg;
            s_decc[tid] = c;
            astoref(ws + OFF_DECH + wpar * 16384 + eb * 1024 + blk * 4 + eu, og * tanhfast(c));
        }
        __syncthreads();  // protect s_part/s_pp against next step's writes
    };

    // location conv: LDS-only, depends on aw(t-1) -> runs BEFORE the A-wait
    auto loc_conv = [&]() {
#pragma unroll 1
        for (int idx = tid; idx < 4096; idx += 512) {
            int f = idx >> 7, tt = idx & 127;
            const float* w0 = s_cw + f * 62;
            float s = 0.f;
#pragma unroll
            for (int k = 0; k < 31; k++) {
                int j = tt + k - 15;
                if (j >= 0 && j < 128) s += w0[k] * s_awl[j] + w0[31 + k] * s_awcl[j];
            }
            s_loc[tt * 33 + f] = s;
        }
    };

    auto attention_rest = [&](int t, int wpar) {
        const int b = blk;
        if (tid < 256)
            *(float4*)(s_ah + tid * 4) =
                aload4(ws + OFF_ATTNH + wpar * 16384 + b * 1024 + tid * 4);
        __syncthreads();
        // query projection pq = h @ query_w^T (L2-cached weights)
#pragma unroll 1
        for (int ii = 0; ii < 16; ii++) {
            int a = wv * 16 + ii;
            const float* qw = A.query_w + a * 1024;
            float s = 0.f;
#pragma unroll
            for (int q = 0; q < 4; q++) {
                int k = q * 256 + l * 4;
                float4 h4 = *reinterpret_cast<const float4*>(&s_ah[k]);
                float4 w4 = *reinterpret_cast<const float4*>(&qw[k]);
                s += dot4f(w4, h4);
            }
#pragma unroll
            for (int off = 1; off < 64; off <<= 1) s += __shfl_xor(s, off);
            if (l == 0) s_pq[a] = s;
        }
        __syncthreads();
        // energies
        {
            int tt = tid >> 2, sl = tid & 3;
            float part = 0.f;
#pragma unroll 1
            for (int i = 0; i < 32; i++) {
                int a = i * 4 + sl;
                float lp = 0.f;
#pragma unroll
                for (int f = 0; f < 32; f++) lp += s_loc[tt * 33 + f] * s_dw[a * 33 + f];
                float arg = s_pq[a] + lp + s_pm[tt * 132 + a];
                part += s_vw[a] * tanhfast(arg);
            }
            s_ep[tid] = part;
        }
        __syncthreads();
        // row-sum + mask + exp (no max-subtraction: |e| bounded ~11, fp32-safe)
        if (tid < 128) {
            float s = s_ep[tid * 4] + s_ep[tid * 4 + 1] + s_ep[tid * 4 + 2] + s_ep[tid * 4 + 3];
            s_aw2[tid] = (tid >= ml) ? 0.f : __expf(s);
        }
        __syncthreads();
        if (wv == 0) {
            float s = s_aw2[l] + s_aw2[l + 64];
#pragma unroll
            for (int off = 1; off < 64; off <<= 1) s += __shfl_xor(s, off);
            if (l == 0) s_red[0] = 1.f / s;
        }
        __syncthreads();
        if (tid < 128) {
            float val = s_aw2[tid] * s_red[0];
            s_aw2[tid] = val;
            s_awl[tid] = val;          // persistent state for t+1
            s_awcl[tid] += val;
            A.out[165888 + b * 16384 + t * 128 + tid] = val;  // alignments
        }
        __syncthreads();
        // context: ctx[e] = sum_t aw2[t] * memory[b][t][e]  (memory L2-cached;
        // unroll 8 kept: these are ordinary cached loads that need ILP)
        {
            const float* mb = A.memory + (size_t)b * 65536 + tid;
            float acc = 0.f;
#pragma unroll 8
            for (int tt2 = 0; tt2 < 128; tt2++) acc += s_aw2[tt2] * mb[tt2 * 512];
            astoref(ws + OFF_CTX + wpar * 8192 + b * 512 + tid, acc);
        }
    };

    auto eout = [&](int tdone) {
        int widx = (blk - 16) * 8 + wv;
        if (widx >= 1296) return;
        int ppar = tdone & 1;
        int b; const float* wrow; float bias; float* dst;
        if (widx < 1280) {
            b = widx / 80; int m = widx % 80;
            wrow = A.proj_w + m * 1536; bias = A.proj_b[m];
            dst = A.out + (size_t)(b * 80 + m) * 128 + tdone;
        } else {
            b = widx - 1280;
            wrow = A.gate_w; bias = A.gate_b[0];
            dst = A.out + 163840 + b * 128 + tdone;
        }
        const float* h1p = ws + OFF_DECH + ppar * 16384 + b * 1024;
        const float* c1p = ws + OFF_CTX + ppar * 8192 + b * 512;
        vf4 h4[6];
#pragma unroll
        for (int q = 0; q < 6; q++) {
            int k = q * 256 + l * 4;
            h4[q] = (k < 1024) ? gload4(h1p + k) : gload4(c1p + k - 1024);
        }
        VMWAIT();
        float s = 0.f;
#pragma unroll
        for (int q = 0; q < 6; q++) {
            int k = q * 256 + l * 4;
            float4 w4 = *reinterpret_cast<const float4*>(&wrow[k]);
            s += dot4v(w4, h4[q]);
        }
#pragma unroll
        for (int off = 1; off < 64; off <<= 1) s += __shfl_xor(s, off);
        if (l == 0) *dst = s + bias;
    };

    // I-FOOTPRINT: single rolled t-loop; dec_partial/dec_tail appear ONCE
    // (shared tail) instead of duplicated in both branch arms.
#pragma unroll 1
    for (int t = 0; t < 128; t++) {
        int wpar = t & 1, rpar = wpar ^ 1;
        unsigned tg = (unsigned)(t + 1);
        attn_stage(t, wpar, rpar);
        __syncthreads();                  // all waves' h_a stores drained
        if (tid == 0) {
            asm volatile("s_waitcnt vmcnt(0)" ::: "memory");
            unsigned old = __hip_atomic_fetch_add(subA, 1u, __ATOMIC_RELAXED,
                                                  __HIP_MEMORY_SCOPE_AGENT);
            if (old == 16u * tg - 1u)
                __hip_atomic_fetch_add(ctrA, 1u, __ATOMIC_RELAXED,
                                       __HIP_MEMORY_SCOPE_AGENT);
        }
        if (blk < 16) {
            loc_conv();                   // LDS-only; overlaps other blocks' stage
            __syncthreads();
            if (tid == 0) {
                wait_ge(ctrA, 16u * tg);  // 16 pollers on this line
                __hip_atomic_store(bcastA + blk * 8, tg, __ATOMIC_RELAXED,
                                   __HIP_MEMORY_SCOPE_AGENT);
                LDS_POST(0, tg);
            } else if (wv > 0) LDS_SPIN(0, (int)tg);
            __syncthreads();
            attention_rest(t, wpar);
            __syncthreads();              // ctx stores drained by all waves
            if (tid == 0) {
                asm volatile("s_waitcnt vmcnt(0)" ::: "memory");
                __hip_atomic_fetch_add(ctrB, 1u, __ATOMIC_RELAXED,
                                       __HIP_MEMORY_SCOPE_AGENT);
            }
        } else {
            if (tid == 0) {
                wait_ge(bcastA + grp * 8, tg);   // <=16 pollers on group line
                LDS_POST(0, tg);
            } else if (wv > 0) LDS_SPIN(0, (int)tg);
            __syncthreads();
            if (t >= 1) eout(t - 1);      // overlaps attention(t)
        }
        dec_partial(wpar, rpar);          // SHARED: overlaps attention / B-hop
        if (blk < 16) {
            if (tid == 0) {
                wait_ge(ctrB, 16u * tg);  // 16 pollers
                __hip_atomic_store(bcastB + blk * 8, tg, __ATOMIC_RELAXED,
                                   __HIP_MEMORY_SCOPE_AGENT);
                LDS_POST(1, tg);
            } else if (wv > 0) LDS_SPIN(1, (int)tg);
        } else {
            if (tid == 0) {
                wait_ge(bcastB + grp * 8, tg);
                LDS_POST(1, tg);
            } else if (wv > 0) LDS_SPIN(1, (int)tg);
        }
        __syncthreads();
        dec_tail(wpar);                   // SHARED
    }
    // final release: h_d(127) drained by dec_tail's barrier
    if (tid == 0) {
        asm volatile("s_waitcnt vmcnt(0)" ::: "memory");
        unsigned old = __hip_atomic_fetch_add(subA, 1u, __ATOMIC_RELAXED,
                                              __HIP_MEMORY_SCOPE_AGENT);
        if (old == 16u * 129u - 1u)
            __hip_atomic_fetch_add(ctrA, 1u, __ATOMIC_RELAXED, __HIP_MEMORY_SCOPE_AGENT);
    }
    if (blk < 16) {
        if (tid == 0) {
            wait_ge(ctrA, 16u * 129u);
            __hip_atomic_store(bcastA + blk * 8, 129u, __ATOMIC_RELAXED,
                               __HIP_MEMORY_SCOPE_AGENT);
        }
    } else {
        if (tid == 0) { wait_ge(bcastA + grp * 8, 129u); LDS_POST(0, 129); }
        else if (wv > 0) LDS_SPIN(0, 129);
        __syncthreads();
        eout(127);
    }
}

// ---------------- launcher ----------------

extern "C" void kernel_launch(void* const* d_in, const int* in_sizes, int n_in,
                              void* d_out, int out_size, void* d_ws, size_t ws_size,
                              hipStream_t stream) {
    (void)in_sizes; (void)n_in; (void)out_size; (void)ws_size;
    const float* memory    = (const float*)d_in[0];
    const float* mels      = (const float*)d_in[1];
    const int*   memlen    = (const int*)d_in[2];
    const float* prenet_w1 = (const float*)d_in[3];
    const float* prenet_w2 = (const float*)d_in[4];
    const float* arnn_wih  = (const float*)d_in[5];
    const float* arnn_whh  = (const float*)d_in[6];
    const float* arnn_bih  = (const float*)d_in[7];
    const float* arnn_bhh  = (const float*)d_in[8];
    const float* query_w   = (const float*)d_in[9];
    const float* memory_w  = (const float*)d_in[10];
    const float* v_w       = (const float*)d_in[11];
    const float* conv_w    = (const float*)d_in[12];
    const float* dense_w   = (const float*)d_in[13];
    const float* drnn_wih  = (const float*)d_in[14];
    const float* drnn_whh  = (const float*)d_in[15];
    const float* drnn_bih  = (const float*)d_in[16];
    const float* drnn_bhh  = (const float*)d_in[17];
    const float* proj_w    = (const float*)d_in[18];
    const float* proj_b    = (const float*)d_in[19];
    const float* gate_w    = (const float*)d_in[20];
    const float* gate_b    = (const float*)d_in[21];
    float* ws = (float*)d_ws;
    float* out = (float*)d_out;

    build_decin<<<dim3(160), dim3(1024), 0, stream>>>(mels, ws + OFF_DECIN);
    // prenet layer 1: [2048,80]@[80,256]^T, relu
    gemm_kernel<<<dim3(4, 32), dim3(256), 0, stream>>>(ws + OFF_DECIN, 80, prenet_w1, 80,
                                                       ws + OFF_H1, 256, 2048, 256, 80,
                                                       nullptr, nullptr, 1);
    // prenet layer 2
    gemm_kernel<<<dim3(4, 32), dim3(256), 0, stream>>>(ws + OFF_H1, 256, prenet_w2, 256,
                                                       ws + OFF_X, 256, 2048, 256, 256,
                                                       nullptr, nullptr, 1);
    // x-part of attention-LSTM gates + both biases
    gemm_kernel<<<dim3(64, 32), dim3(256), 0, stream>>>(ws + OFF_X, 256, arnn_wih, 768,
                                                        ws + OFF_XA, 4096, 2048, 4096, 256,
                                                        arnn_bih, arnn_bhh, 0);
    // processed memory
    gemm_kernel<<<dim3(2, 32), dim3(256), 0, stream>>>(memory, 512, memory_w, 512,
                                                       ws + OFF_PM, 128, 2048, 128, 512,
                                                       nullptr, nullptr, 0);

    DecArgs a;
    a.memory = memory; a.memlen = memlen;
    a.arnn_wih = arnn_wih; a.arnn_whh = arnn_whh;
    a.drnn_wih = drnn_wih; a.drnn_whh = drnn_whh;
    a.drnn_bih = drnn_bih; a.drnn_bhh = drnn_bhh;
    a.query_w = query_w; a.v_w = v_w;
    a.conv_w = conv_w; a.dense_w = dense_w;
    a.proj_w = proj_w; a.proj_b = proj_b;
    a.gate_w = gate_w; a.gate_b = gate_b;
    a.ws = ws; a.out = out;
    void* kargs[] = { &a };
    hipLaunchCooperativeKernel((const void*)decoder_main, dim3(256), dim3(512),
                               kargs, 0, stream);
}

// Round 16
// 10586.581 us; speedup vs baseline: 1.0085x; 1.0085x over previous
//
#include <hip/hip_runtime.h>
#include <hip/hip_cooperative_groups.h>

namespace cg = cooperative_groups;

// Problem constants
#define N_MEL 80
#define ENC   512
#define ARNN  1024
#define PRE   256
#define ADIM  128
#define NFILT 32
#define KS    31
#define BSZ   16
#define TENC  128
#define TDEC  128

// Workspace layout (float offsets)
#define OFF_XA     0u          // [128][16][4096] precomputed x@Wih_x^T + bih + bhh
#define OFF_X      8388608u    // [128][16][256]  prenet out
#define OFF_H1     8912896u    // [128][16][256]  prenet hidden
#define OFF_DECIN  9437184u    // [128][16][80]
#define OFF_PM     9601024u    // [16][128][128]  processed memory
#define OFF_ATTNH  9863168u    // [2][16][1024]
#define OFF_DECH   9895936u    // [2][16][1024]
#define OFF_CTX    9928704u    // [2][16][512]
#define OFF_CTR    9945088u    // master@0 ctrB@32 subA@64+g*32 bcastA@576+g*32 bcastB@1088+g*32
#define STATE_FLOATS 83520     // OFF_ATTNH .. end of counter/broadcast region

typedef unsigned long long u64;
typedef float vf4 __attribute__((ext_vector_type(4)));   // TRUE vector -> VReg_128 in asm

__device__ __forceinline__ float sigmf(float x) { return 1.0f / (1.0f + __expf(-x)); }
__device__ __forceinline__ float tanhfast(float x) { return 1.0f - 2.0f / (__expf(2.0f * x) + 1.0f); }
__device__ __forceinline__ float dot4f(const float4& w, const float4& x) {
    return w.x * x.x + w.y * x.y + w.z * x.z + w.w * x.w;
}
__device__ __forceinline__ float dot4v(const float4& w, const vf4& x) {
    return w.x * x[0] + w.y * x[1] + w.z * x[2] + w.w * x[3];
}

// Coherent PIPELINED load (round 13, proven): plain global_load, sc0|sc1,
// vmcnt-only. Result invalid until VMWAIT().
__device__ __forceinline__ vf4 gload4(const float* p) {
    vf4 v;
    asm volatile("global_load_dwordx4 %0, %1, off sc0 sc1" : "=&v"(v) : "v"(p));
    return v;
}
#define VMWAIT()                                                                 \
    do {                                                                         \
        asm volatile("s_waitcnt vmcnt(0)" ::: "memory");                         \
        __builtin_amdgcn_sched_barrier(0);                                       \
    } while (0)

// coherent single-float store (compiler-tracked -> drained before barriers)
union F1U { unsigned u; float f; };
__device__ __forceinline__ void astoref(float* p, float v) {
    F1U c; c.f = v;
    __hip_atomic_store((unsigned*)p, c.u, __ATOMIC_RELAXED, __HIP_MEMORY_SCOPE_AGENT);
}
union F2U { u64 u; float f[2]; };
__device__ __forceinline__ float4 aload4(const float* p) {
    F2U a, b;
    a.u = __hip_atomic_load((const u64*)p,     __ATOMIC_RELAXED, __HIP_MEMORY_SCOPE_AGENT);
    b.u = __hip_atomic_load((const u64*)p + 1, __ATOMIC_RELAXED, __HIP_MEMORY_SCOPE_AGENT);
    return make_float4(a.f[0], a.f[1], b.f[0], b.f[1]);
}

// global poll (tid0 only; <=16 pollers per line by construction)
__device__ __forceinline__ void wait_ge(unsigned* p, unsigned tgt) {
    while (__hip_atomic_load(p, __ATOMIC_RELAXED, __HIP_MEMORY_SCOPE_AGENT) < tgt)
        __builtin_amdgcn_s_sleep(1);
    asm volatile("" ::: "memory");
}

// LDS epoch spin (direct shared-array access; no generic pointer — gfx950 isel bug)
#define LDS_SPIN(idx, tgt)                                                      \
    do {                                                                        \
        while (__hip_atomic_load(&s_done[idx], __ATOMIC_RELAXED,                \
                                 __HIP_MEMORY_SCOPE_WORKGROUP) < (tgt))         \
            __builtin_amdgcn_s_sleep(1);                                        \
        asm volatile("" ::: "memory");                                          \
    } while (0)

#define LDS_POST(idx, val)                                                      \
    __hip_atomic_store(&s_done[idx], (int)(val), __ATOMIC_RELAXED,              \
                       __HIP_MEMORY_SCOPE_WORKGROUP)

// ---------------- precompute kernels (unchanged) ----------------

__global__ void __launch_bounds__(1024) build_decin(const float* __restrict__ mels,
                                                    float* __restrict__ decin) {
    int idx = blockIdx.x * 1024 + threadIdx.x;  // 128*16*80 = 163840
    if (idx >= 128 * 16 * 80) return;
    int t = idx / 1280, r = idx % 1280;
    int b = r / 80, m = r % 80;
    decin[idx] = (t == 0) ? 0.f : mels[b * (80 * 128) + m * 128 + (t - 1)];
}

__global__ void __launch_bounds__(256) gemm_kernel(
    const float* __restrict__ A, int lda,
    const float* __restrict__ B, int ldb,
    float* __restrict__ C, int ldc,
    int M, int N, int K,
    const float* __restrict__ bias1, const float* __restrict__ bias2, int relu) {
    __shared__ float As[16][68];
    __shared__ float Bs[16][68];
    int tid = threadIdx.x;
    int tn = tid & 15, tm = tid >> 4;
    int m0 = blockIdx.y * 64, n0 = blockIdx.x * 64;
    float acc[4][4] = {};
    for (int k0 = 0; k0 < K; k0 += 16) {
        for (int idx = tid; idx < 1024; idx += 256) {
            int mm = idx >> 4, kk = idx & 15;
            int kg = k0 + kk;
            As[kk][mm] = (kg < K) ? A[(size_t)(m0 + mm) * lda + kg] : 0.f;
            Bs[kk][mm] = (kg < K) ? B[(size_t)(n0 + mm) * ldb + kg] : 0.f;
        }
        __syncthreads();
#pragma unroll
        for (int kk = 0; kk < 16; kk++) {
            float av[4], bv[4];
#pragma unroll
            for (int i = 0; i < 4; i++) { av[i] = As[kk][tm * 4 + i]; bv[i] = Bs[kk][tn * 4 + i]; }
#pragma unroll
            for (int i = 0; i < 4; i++)
#pragma unroll
                for (int j = 0; j < 4; j++) acc[i][j] += av[i] * bv[j];
        }
        __syncthreads();
    }
    for (int i = 0; i < 4; i++) {
        int m = m0 + tm * 4 + i;
        for (int j = 0; j < 4; j++) {
            int n = n0 + tn * 4 + j;
            float v = acc[i][j];
            if (bias1) v += bias1[n];
            if (bias2) v += bias2[n];
            if (relu) v = fmaxf(v, 0.f);
            C[(size_t)m * ldc + n] = v;
        }
    }
}

// ---------------- main persistent cooperative kernel ----------------

struct DecArgs {
    const float* memory;
    const int* memlen;
    const float* arnn_wih;
    const float* arnn_whh;
    const float* drnn_wih;
    const float* drnn_whh;
    const float* drnn_bih;
    const float* drnn_bhh;
    const float* query_w;
    const float* v_w;
    const float* conv_w;
    const float* dense_w;
    const float* proj_w;
    const float* proj_b;
    const float* gate_w;
    const float* gate_b;
    float* ws;
    float* out;
};

// amdgpu_waves_per_eu(2,2): pin occupancy at exactly 2 waves/SIMD (the only
// level the 120-KB-LDS block can have anyway). VGPR cap = 512/2 = 256/wave,
// and the allocator may USE up to 256 (round 13's (512,2) promise made it
// allocate only 128 — forcing the 128-VGPR wA/wD "persistent" weights to be
// re-loaded from L2 inside every phase, the in-phase stall measured in round
// 11). Max=2 also prevents round-15's failure mode (allocation >256 -> 8-wave
// block unlaunchable -> silent zeros via the discarded launch return code).
__global__ void __attribute__((amdgpu_flat_work_group_size(512, 512),
                               amdgpu_waves_per_eu(2, 2)))
decoder_main(DecArgs A) {
    cg::grid_group grid = cg::this_grid();
    const int tid = threadIdx.x;
    const int wv = tid >> 6;
    const int l = tid & 63;
    const int blk = blockIdx.x;
    const int u = wv & 3;          // unit within block's 4
    const int kq = wv >> 2;        // K-half {0,1}
    const int jj = blk * 4 + u;    // global hidden-unit id
    const int col = kq * 256 + l * 4;  // column within a 512-wide channel
    float* ws = A.ws;
    unsigned* ctrA = (unsigned*)(ws + OFF_CTR);        // master: 16 adds/step
    unsigned* ctrB = (unsigned*)(ws + OFF_CTR + 32);   // 16 adds/step
    const int grp = blk >> 4;
    unsigned* subA   = (unsigned*)(ws + OFF_CTR + 64 + grp * 32);
    unsigned* bcastA = (unsigned*)(ws + OFF_CTR + 576);   // +idx*32
    unsigned* bcastB = (unsigned*)(ws + OFF_CTR + 1088);  // +idx*32

    // LDS (~123 KB, 1 block/CU)
    __shared__ float s_pm[128 * 132];   // processed memory, padded (attn blocks)
    __shared__ float s_loc[128 * 33];
    __shared__ float s_dw[128 * 33];    // dense_w padded, persistent
    __shared__ float s_cw[1984];        // conv_w persistent (attn blocks)
    __shared__ float s_ah[1024];
    __shared__ float s_ep[512];
    __shared__ float s_part[8][64];     // LSTM partials [wave][b*4+gate]
    __shared__ float s_pp[8][64];       // dec partial (h_a,h_d channels)
    __shared__ float s_pq[128];
    __shared__ float s_aw2[128];
    __shared__ float s_awl[128];        // persistent aw state (attn blocks)
    __shared__ float s_awcl[128];       // persistent cumulative aw
    __shared__ float s_attnc[64];       // persistent attn LSTM c, [eu*16+eb]
    __shared__ float s_decc[64];        // persistent dec  LSTM c
    __shared__ float s_db[16];          // dec biases [u*4+g]
    __shared__ float s_vw[128];
    __shared__ float s_red[2];
    __shared__ int   s_done[2];         // LDS epoch mirrors of the two hops

    // ---- init: zero recurrent state + counters (ws poisoned before each call) ----
    {
        int g = blk * 512 + tid;
        if (g < STATE_FLOATS) ws[OFF_ATTNH + g] = 0.f;
    }
    if (tid < 2) s_done[tid] = 0;
    if (tid < 128) { s_awl[tid] = 0.f; s_awcl[tid] = 0.f; }
    if (tid < 64) { s_attnc[tid] = 0.f; s_decc[tid] = 0.f; }
    if (tid < 16) {
        int uu = tid >> 2, gg = tid & 3;
        s_db[tid] = A.drnn_bih[gg * 1024 + blk * 4 + uu] + A.drnn_bhh[gg * 1024 + blk * 4 + uu];
    }
    if (tid < 128) s_vw[tid] = A.v_w[tid];
    for (int idx = tid; idx < 4096; idx += 512) {
        int a = idx >> 5, f = idx & 31;
        s_dw[a * 33 + f] = A.dense_w[idx];
    }
    if (blk < 16) {
        for (int idx = tid; idx < 16384; idx += 512) {
            int tt = idx >> 7, a = idx & 127;
            s_pm[tt * 132 + a] = ws[OFF_PM + (blk * 128 + tt) * 128 + a];
        }
        for (int idx = tid; idx < 1984; idx += 512) s_cw[idx] = A.conv_w[idx];
    }
    const int ml = (blk < 16) ? A.memlen[blk] : 0;

    // ---- load persistent weight registers (once; 128 floats/thread) ----
    float4 wA[12];  // attn LSTM [ch*4+g], ch: ctx, h0, h1
    {
#pragma unroll
        for (int g = 0; g < 4; g++)
            wA[g] = *reinterpret_cast<const float4*>(
                A.arnn_wih + (size_t)(g * 1024 + jj) * 768 + 256 + col);
#pragma unroll
        for (int ch = 1; ch < 3; ch++)
#pragma unroll
            for (int g = 0; g < 4; g++)
                wA[ch * 4 + g] = *reinterpret_cast<const float4*>(
                    A.arnn_whh + (size_t)(g * 1024 + jj) * 1024 + (ch - 1) * 512 + col);
    }
    float4 wD[20];  // dec LSTM ch: ha0, ha1, ctx, hd0, hd1
    {
#pragma unroll
        for (int ch = 0; ch < 3; ch++)
#pragma unroll
            for (int g = 0; g < 4; g++)
                wD[ch * 4 + g] = *reinterpret_cast<const float4*>(
                    A.drnn_wih + (size_t)(g * 1024 + jj) * 1536 + ch * 512 + col);
#pragma unroll
        for (int ch = 3; ch < 5; ch++)
#pragma unroll
            for (int g = 0; g < 4; g++)
                wD[ch * 4 + g] = *reinterpret_cast<const float4*>(
                    A.drnn_whh + (size_t)(g * 1024 + jj) * 1024 + (ch - 3) * 512 + col);
    }
    __syncthreads();
    grid.sync();   // single cg barrier: init (incl. counters/broadcast) visible

    // packed butterfly: 4 gate-partials over 64 lanes -> lane l holds gate (l&3)
    auto reduce4 = [&](float p0, float p1, float p2, float p3) -> float {
        float a01 = (l & 1) ? p1 : p0;
        float b01 = (l & 1) ? p0 : p1;
        a01 += __shfl_xor(b01, 1);
        float a23 = (l & 1) ? p3 : p2;
        float b23 = (l & 1) ? p2 : p3;
        a23 += __shfl_xor(b23, 1);
        float k_ = (l & 2) ? a23 : a01;
        float s_ = (l & 2) ? a01 : a23;
        k_ += __shfl_xor(s_, 2);
        k_ += __shfl_xor(k_, 4);
        k_ += __shfl_xor(k_, 8);
        k_ += __shfl_xor(k_, 16);
        k_ += __shfl_xor(k_, 32);
        return k_;
    };

    auto attn_stage = [&](int t, int wpar, int rpar) {
        const float* hb = ws + OFF_ATTNH + rpar * 16384;
        const float* cb = ws + OFF_CTX + rpar * 8192;
        float xa0 = 0.f, xa1 = 0.f, xa2 = 0.f, xa3 = 0.f;
        if (tid < 64) {
            int eb = tid & 15, eu = tid >> 4;
            const float* xa = ws + OFF_XA + (size_t)(t * 16 + eb) * 4096 + (blk * 4 + eu);
            xa0 = xa[0]; xa1 = xa[1024]; xa2 = xa[2048]; xa3 = xa[3072];
        }
#pragma unroll
        for (int c = 0; c < 4; c++) {
            vf4 x[12];
#pragma unroll
            for (int bl = 0; bl < 4; bl++) {
                int b = c * 4 + bl;
                x[bl * 3 + 0] = gload4(cb + b * 512 + col);
                x[bl * 3 + 1] = gload4(hb + b * 1024 + col);
                x[bl * 3 + 2] = gload4(hb + b * 1024 + 512 + col);
            }
            VMWAIT();   // 12 loads in flight -> one wait per 4-batch group
#pragma unroll
            for (int bl = 0; bl < 4; bl++) {
                int b = c * 4 + bl;
                float p0 = dot4v(wA[0], x[bl*3]) + dot4v(wA[4], x[bl*3+1]) + dot4v(wA[8],  x[bl*3+2]);
                float p1 = dot4v(wA[1], x[bl*3]) + dot4v(wA[5], x[bl*3+1]) + dot4v(wA[9],  x[bl*3+2]);
                float p2 = dot4v(wA[2], x[bl*3]) + dot4v(wA[6], x[bl*3+1]) + dot4v(wA[10], x[bl*3+2]);
                float p3 = dot4v(wA[3], x[bl*3]) + dot4v(wA[7], x[bl*3+1]) + dot4v(wA[11], x[bl*3+2]);
                float r = reduce4(p0, p1, p2, p3);
                if (l < 4) s_part[wv][b * 4 + l] = r;
            }
        }
        __syncthreads();
        if (tid < 64) {
            int eu = tid >> 4, eb = tid & 15;
            float G0 = s_part[eu][eb * 4 + 0] + s_part[eu + 4][eb * 4 + 0] + xa0;
            float G1 = s_part[eu][eb * 4 + 1] + s_part[eu + 4][eb * 4 + 1] + xa1;
            float G2 = s_part[eu][eb * 4 + 2] + s_part[eu + 4][eb * 4 + 2] + xa2;
            float G3 = s_part[eu][eb * 4 + 3] + s_part[eu + 4][eb * 4 + 3] + xa3;
            float ig = sigmf(G0), fg = sigmf(G1), gg = tanhfast(G2), og = sigmf(G3);
            float c = fg * s_attnc[tid] + ig * gg;
            s_attnc[tid] = c;
            astoref(ws + OFF_ATTNH + wpar * 16384 + eb * 1024 + blk * 4 + eu, og * tanhfast(c));
        }
    };

    auto dec_partial = [&](int wpar, int rpar) {
        const float* hb = ws + OFF_ATTNH + wpar * 16384;
        const float* db = ws + OFF_DECH + rpar * 16384;
#pragma unroll
        for (int c = 0; c < 8; c++) {   // 2-batch groups: 8 loads in flight
            vf4 x[8];
#pragma unroll
            for (int bl = 0; bl < 2; bl++) {
                int b = c * 2 + bl;
                x[bl * 4 + 0] = gload4(hb + b * 1024 + col);
                x[bl * 4 + 1] = gload4(hb + b * 1024 + 512 + col);
                x[bl * 4 + 2] = gload4(db + b * 1024 + col);
                x[bl * 4 + 3] = gload4(db + b * 1024 + 512 + col);
            }
            VMWAIT();
#pragma unroll
            for (int bl = 0; bl < 2; bl++) {
                int b = c * 2 + bl;
                float p0 = dot4v(wD[0], x[bl*4]) + dot4v(wD[4], x[bl*4+1]) + dot4v(wD[12], x[bl*4+2]) + dot4v(wD[16], x[bl*4+3]);
                float p1 = dot4v(wD[1], x[bl*4]) + dot4v(wD[5], x[bl*4+1]) + dot4v(wD[13], x[bl*4+2]) + dot4v(wD[17], x[bl*4+3]);
                float p2 = dot4v(wD[2], x[bl*4]) + dot4v(wD[6], x[bl*4+1]) + dot4v(wD[14], x[bl*4+2]) + dot4v(wD[18], x[bl*4+3]);
                float p3 = dot4v(wD[3], x[bl*4]) + dot4v(wD[7], x[bl*4+1]) + dot4v(wD[15], x[bl*4+2]) + dot4v(wD[19], x[bl*4+3]);
                float r = reduce4(p0, p1, p2, p3);
                if (l < 4) s_pp[wv][b * 4 + l] = r;
            }
        }
    };

    auto dec_tail = [&](int wpar) {
        const float* cb = ws + OFF_CTX + wpar * 8192;
#pragma unroll
        for (int c = 0; c < 2; c++) {
            vf4 xc[8];
#pragma unroll
            for (int bl = 0; bl < 8; bl++) xc[bl] = gload4(cb + (c * 8 + bl) * 512 + col);
            VMWAIT();
#pragma unroll
            for (int bl = 0; bl < 8; bl++) {
                int b = c * 8 + bl;
                float p0 = dot4v(wD[8], xc[bl]);
                float p1 = dot4v(wD[9], xc[bl]);
                float p2 = dot4v(wD[10], xc[bl]);
                float p3 = dot4v(wD[11], xc[bl]);
                float r = reduce4(p0, p1, p2, p3);
                if (l < 4) s_part[wv][b * 4 + l] = r;
            }
        }
        __syncthreads();
        if (tid < 64) {
            int eu = tid >> 4, eb = tid & 15;
            float G0 = s_part[eu][eb * 4 + 0] + s_part[eu + 4][eb * 4 + 0]
                     + s_pp[eu][eb * 4 + 0] + s_pp[eu + 4][eb * 4 + 0] + s_db[eu * 4 + 0];
            float G1 = s_part[eu][eb * 4 + 1] + s_part[eu + 4][eb * 4 + 1]
                     + s_pp[eu][eb * 4 + 1] + s_pp[eu + 4][eb * 4 + 1] + s_db[eu * 4 + 1];
            float G2 = s_part[eu][eb * 4 + 2] + s_part[eu + 4][eb * 4 + 2]
                     + s_pp[eu][eb * 4 + 2] + s_pp[eu + 4][eb * 4 + 2] + s_db[eu * 4 + 2];
            float G3 = s_part[eu][eb * 4 + 3] + s_part[eu + 4][eb * 4 + 3]
                     + s_pp[eu][eb * 4 + 3] + s_pp[eu + 4][eb * 4 + 3] + s_db[eu * 4 + 3];
            float ig = sigmf(G0), fg = sigmf(G1), gg = tanhfast(G2), og = sigmf(G3);
            float c = fg * s_decc[tid] + ig * gg;
            s_decc[tid] = c;
            astoref(ws + OFF_DECH + wpar * 16384 + eb * 1024 + blk * 4 + eu, og * tanhfast(c));
        }
        __syncthreads();  // protect s_part/s_pp against next step's writes
    };

    // location conv: LDS-only, depends on aw(t-1) -> runs BEFORE the A-wait
    auto loc_conv = [&]() {
        for (int idx = tid; idx < 4096; idx += 512) {
            int f = idx >> 7, tt = idx & 127;
            const float* w0 = s_cw + f * 62;
            float s = 0.f;
#pragma unroll
            for (int k = 0; k < 31; k++) {
                int j = tt + k - 15;
                if (j >= 0 && j < 128) s += w0[k] * s_awl[j] + w0[31 + k] * s_awcl[j];
            }
            s_loc[tt * 33 + f] = s;
        }
    };

    auto attention_rest = [&](int t, int wpar) {
        const int b = blk;
        if (tid < 256)
            *(float4*)(s_ah + tid * 4) =
                aload4(ws + OFF_ATTNH + wpar * 16384 + b * 1024 + tid * 4);
        __syncthreads();
        // query projection pq = h @ query_w^T (L2-cached weights)
#pragma unroll 4
        for (int ii = 0; ii < 16; ii++) {
            int a = wv * 16 + ii;
            const float* qw = A.query_w + a * 1024;
            float s = 0.f;
#pragma unroll
            for (int q = 0; q < 4; q++) {
                int k = q * 256 + l * 4;
                float4 h4 = *reinterpret_cast<const float4*>(&s_ah[k]);
                float4 w4 = *reinterpret_cast<const float4*>(&qw[k]);
                s += dot4f(w4, h4);
            }
#pragma unroll
            for (int off = 1; off < 64; off <<= 1) s += __shfl_xor(s, off);
            if (l == 0) s_pq[a] = s;
        }
        __syncthreads();
        // energies
        {
            int tt = tid >> 2, sl = tid & 3;
            float part = 0.f;
            for (int i = 0; i < 32; i++) {
                int a = i * 4 + sl;
                float lp = 0.f;
#pragma unroll
                for (int f = 0; f < 32; f++) lp += s_loc[tt * 33 + f] * s_dw[a * 33 + f];
                float arg = s_pq[a] + lp + s_pm[tt * 132 + a];
                part += s_vw[a] * tanhfast(arg);
            }
            s_ep[tid] = part;
        }
        __syncthreads();
        // row-sum + mask + exp (no max-subtraction: |e| bounded ~11, fp32-safe)
        if (tid < 128) {
            float s = s_ep[tid * 4] + s_ep[tid * 4 + 1] + s_ep[tid * 4 + 2] + s_ep[tid * 4 + 3];
            s_aw2[tid] = (tid >= ml) ? 0.f : __expf(s);
        }
        __syncthreads();
        if (wv == 0) {
            float s = s_aw2[l] + s_aw2[l + 64];
#pragma unroll
            for (int off = 1; off < 64; off <<= 1) s += __shfl_xor(s, off);
            if (l == 0) s_red[0] = 1.f / s;
        }
        __syncthreads();
        if (tid < 128) {
            float val = s_aw2[tid] * s_red[0];
            s_aw2[tid] = val;
            s_awl[tid] = val;          // persistent state for t+1
            s_awcl[tid] += val;
            A.out[165888 + b * 16384 + t * 128 + tid] = val;  // alignments
        }
        __syncthreads();
        // context: ctx[e] = sum_t aw2[t] * memory[b][t][e]  (memory L2-cached)
        {
            const float* mb = A.memory + (size_t)b * 65536 + tid;
            float acc = 0.f;
#pragma unroll 8
            for (int tt2 = 0; tt2 < 128; tt2++) acc += s_aw2[tt2] * mb[tt2 * 512];
            astoref(ws + OFF_CTX + wpar * 8192 + b * 512 + tid, acc);
        }
    };

    auto eout = [&](int tdone) {
        int widx = (blk - 16) * 8 + wv;
        if (widx >= 1296) return;
        int ppar = tdone & 1;
        int b; const float* wrow; float bias; float* dst;
        if (widx < 1280) {
            b = widx / 80; int m = widx % 80;
            wrow = A.proj_w + m * 1536; bias = A.proj_b[m];
            dst = A.out + (size_t)(b * 80 + m) * 128 + tdone;
        } else {
            b = widx - 1280;
            wrow = A.gate_w; bias = A.gate_b[0];
            dst = A.out + 163840 + b * 128 + tdone;
        }
        const float* h1p = ws + OFF_DECH + ppar * 16384 + b * 1024;
        const float* c1p = ws + OFF_CTX + ppar * 8192 + b * 512;
        vf4 h4[6];
#pragma unroll
        for (int q = 0; q < 6; q++) {
            int k = q * 256 + l * 4;
            h4[q] = (k < 1024) ? gload4(h1p + k) : gload4(c1p + k - 1024);
        }
        VMWAIT();
        float s = 0.f;
#pragma unroll
        for (int q = 0; q < 6; q++) {
            int k = q * 256 + l * 4;
            float4 w4 = *reinterpret_cast<const float4*>(&wrow[k]);
            s += dot4v(w4, h4[q]);
        }
#pragma unroll
        for (int off = 1; off < 64; off <<= 1) s += __shfl_xor(s, off);
        if (l == 0) *dst = s + bias;
    };

    for (int t = 0; t < 128; t++) {
        int wpar = t & 1, rpar = wpar ^ 1;
        unsigned tg = (unsigned)(t + 1);
        attn_stage(t, wpar, rpar);
        __syncthreads();                  // all waves' h_a stores drained
        if (tid == 0) {
            asm volatile("s_waitcnt vmcnt(0)" ::: "memory");
            unsigned old = __hip_atomic_fetch_add(subA, 1u, __ATOMIC_RELAXED,
                                                  __HIP_MEMORY_SCOPE_AGENT);
            if (old == 16u * tg - 1u)
                __hip_atomic_fetch_add(ctrA, 1u, __ATOMIC_RELAXED,
                                       __HIP_MEMORY_SCOPE_AGENT);
        }
        if (blk < 16) {
            loc_conv();                   // LDS-only; overlaps other blocks' stage
            __syncthreads();
            if (tid == 0) {
                wait_ge(ctrA, 16u * tg);  // 16 pollers on this line
                __hip_atomic_store(bcastA + blk * 8, tg, __ATOMIC_RELAXED,
                                   __HIP_MEMORY_SCOPE_AGENT);
                LDS_POST(0, tg);
            } else if (wv > 0) LDS_SPIN(0, (int)tg);
            __syncthreads();
            attention_rest(t, wpar);
            __syncthreads();              // ctx stores drained by all waves
            if (tid == 0) {
                asm volatile("s_waitcnt vmcnt(0)" ::: "memory");
                __hip_atomic_fetch_add(ctrB, 1u, __ATOMIC_RELAXED,
                                       __HIP_MEMORY_SCOPE_AGENT);
            }
            dec_partial(wpar, rpar);      // overlaps other attn blocks' ctx
            if (tid == 0) {
                wait_ge(ctrB, 16u * tg);  // 16 pollers
                __hip_atomic_store(bcastB + blk * 8, tg, __ATOMIC_RELAXED,
                                   __HIP_MEMORY_SCOPE_AGENT);
                LDS_POST(1, tg);
            } else if (wv > 0) LDS_SPIN(1, (int)tg);
            __syncthreads();
            dec_tail(wpar);
        } else {
            if (tid == 0) {
                wait_ge(bcastA + grp * 8, tg);   // <=16 pollers on group line
                LDS_POST(0, tg);
            } else if (wv > 0) LDS_SPIN(0, (int)tg);
            __syncthreads();
            if (t >= 1) eout(t - 1);      // overlaps attention(t)
            dec_partial(wpar, rpar);      // overlaps attention(t) + B-hop
            if (tid == 0) {
                wait_ge(bcastB + grp * 8, tg);
                LDS_POST(1, tg);
            } else if (wv > 0) LDS_SPIN(1, (int)tg);
            __syncthreads();
            dec_tail(wpar);
        }
    }
    // final release: h_d(127) drained by dec_tail's barrier
    if (tid == 0) {
        asm volatile("s_waitcnt vmcnt(0)" ::: "memory");
        unsigned old = __hip_atomic_fetch_add(subA, 1u, __ATOMIC_RELAXED,
                                              __HIP_MEMORY_SCOPE_AGENT);
        if (old == 16u * 129u - 1u)
            __hip_atomic_fetch_add(ctrA, 1u, __ATOMIC_RELAXED, __HIP_MEMORY_SCOPE_AGENT);
    }
    if (blk < 16) {
        if (tid == 0) {
            wait_ge(ctrA, 16u * 129u);
            __hip_atomic_store(bcastA + blk * 8, 129u, __ATOMIC_RELAXED,
                               __HIP_MEMORY_SCOPE_AGENT);
        }
    } else {
        if (tid == 0) { wait_ge(bcastA + grp * 8, 129u); LDS_POST(0, 129); }
        else if (wv > 0) LDS_SPIN(0, 129);
        __syncthreads();
        eout(127);
    }
}

// ---------------- launcher ----------------

extern "C" void kernel_launch(void* const* d_in, const int* in_sizes, int n_in,
                              void* d_out, int out_size, void* d_ws, size_t ws_size,
                              hipStream_t stream) {
    (void)in_sizes; (void)n_in; (void)out_size; (void)ws_size;
    const float* memory    = (const float*)d_in[0];
    const float* mels      = (const float*)d_in[1];
    const int*   memlen    = (const int*)d_in[2];
    const float* prenet_w1 = (const float*)d_in[3];
    const float* prenet_w2 = (const float*)d_in[4];
    const float* arnn_wih  = (const float*)d_in[5];
    const float* arnn_whh  = (const float*)d_in[6];
    const float* arnn_bih  = (const float*)d_in[7];
    const float* arnn_bhh  = (const float*)d_in[8];
    const float* query_w   = (const float*)d_in[9];
    const float* memory_w  = (const float*)d_in[10];
    const float* v_w       = (const float*)d_in[11];
    const float* conv_w    = (const float*)d_in[12];
    const float* dense_w   = (const float*)d_in[13];
    const float* drnn_wih  = (const float*)d_in[14];
    const float* drnn_whh  = (const float*)d_in[15];
    const float* drnn_bih  = (const float*)d_in[16];
    const float* drnn_bhh  = (const float*)d_in[17];
    const float* proj_w    = (const float*)d_in[18];
    const float* proj_b    = (const float*)d_in[19];
    const float* gate_w    = (const float*)d_in[20];
    const float* gate_b    = (const float*)d_in[21];
    float* ws = (float*)d_ws;
    float* out = (float*)d_out;

    build_decin<<<dim3(160), dim3(1024), 0, stream>>>(mels, ws + OFF_DECIN);
    // prenet layer 1: [2048,80]@[80,256]^T, relu
    gemm_kernel<<<dim3(4, 32), dim3(256), 0, stream>>>(ws + OFF_DECIN, 80, prenet_w1, 80,
                                                       ws + OFF_H1, 256, 2048, 256, 80,
                                                       nullptr, nullptr, 1);
    // prenet layer 2
    gemm_kernel<<<dim3(4, 32), dim3(256), 0, stream>>>(ws + OFF_H1, 256, prenet_w2, 256,
                                                       ws + OFF_X, 256, 2048, 256, 256,
                                                       nullptr, nullptr, 1);
    // x-part of attention-LSTM gates + both biases
    gemm_kernel<<<dim3(64, 32), dim3(256), 0, stream>>>(ws + OFF_X, 256, arnn_wih, 768,
                                                        ws + OFF_XA, 4096, 2048, 4096, 256,
                                                        arnn_bih, arnn_bhh, 0);
    // processed memory
    gemm_kernel<<<dim3(2, 32), dim3(256), 0, stream>>>(memory, 512, memory_w, 512,
                                                       ws + OFF_PM, 128, 2048, 128, 512,
                                                       nullptr, nullptr, 0);

    DecArgs a;
    a.memory = memory; a.memlen = memlen;
    a.arnn_wih = arnn_wih; a.arnn_whh = arnn_whh;
    a.drnn_wih = drnn_wih; a.drnn_whh = drnn_whh;
    a.drnn_bih = drnn_bih; a.drnn_bhh = drnn_bhh;
    a.query_w = query_w; a.v_w = v_w;
    a.conv_w = conv_w; a.dense_w = dense_w;
    a.proj_w = proj_w; a.proj_b = proj_b;
    a.gate_w = gate_w; a.gate_b = gate_b;
    a.ws = ws; a.out = out;
    void* kargs[] = { &a };
    hipLaunchCooperativeKernel((const void*)decoder_main, dim3(256), dim3(512),
                               kargs, 0, stream);
}

// Round 17
// 10519.326 us; speedup vs baseline: 1.0150x; 1.0064x over previous
//
#include <hip/hip_runtime.h>
#include <hip/hip_cooperative_groups.h>

namespace cg = cooperative_groups;

// Problem constants
#define N_MEL 80
#define ENC   512
#define ARNN  1024
#define PRE   256
#define ADIM  128
#define NFILT 32
#define KS    31
#define BSZ   16
#define TENC  128
#define TDEC  128

// Workspace layout (float offsets)
#define OFF_XA     0u          // [128][16][4096] precomputed x@Wih_x^T + bih + bhh
#define OFF_X      8388608u    // [128][16][256]  prenet out
#define OFF_H1     8912896u    // [128][16][256]  prenet hidden
#define OFF_DECIN  9437184u    // [128][16][80]
#define OFF_PM     9601024u    // [16][128][128]  processed memory
#define OFF_ATTNH  9863168u    // [2][16][1024]
#define OFF_DECH   9895936u    // [2][16][1024]
#define OFF_CTX    9928704u    // [2][16][512]
#define OFF_CTR    9945088u    // master@0 ctrB@32 subA@64+g*32 bcastA@576+g*32 bcastB@1088+g*32
#define STATE_FLOATS 83520     // OFF_ATTNH .. end of counter/broadcast region

typedef unsigned long long u64;
typedef float vf4 __attribute__((ext_vector_type(4)));   // TRUE vector -> VReg_128 in asm

__device__ __forceinline__ float sigmf(float x) { return 1.0f / (1.0f + __expf(-x)); }
__device__ __forceinline__ float tanhfast(float x) { return 1.0f - 2.0f / (__expf(2.0f * x) + 1.0f); }
__device__ __forceinline__ float dot4f(const float4& w, const float4& x) {
    return w.x * x.x + w.y * x.y + w.z * x.z + w.w * x.w;
}
__device__ __forceinline__ float dotvv(const vf4& w, const vf4& x) {
    return w[0] * x[0] + w[1] * x[1] + w[2] * x[2] + w[3] * x[3];
}

// Coherent PIPELINED load (round 13, proven): plain global_load, sc0|sc1,
// vmcnt-only. Result invalid until VMWAIT(). ALSO used for the persistent
// weights: an asm-volatile def cannot be rematerialized by the scheduler, so
// the weight values MUST stay register-allocated (the plain-load versions were
// silently re-loaded from L2 inside every phase — VGPR_Count stuck at 128
// across rounds 13-16 proves it, since wA/wD alone need 128 regs).
__device__ __forceinline__ vf4 gload4(const float* p) {
    vf4 v;
    asm volatile("global_load_dwordx4 %0, %1, off sc0 sc1" : "=&v"(v) : "v"(p));
    return v;
}
#define VMWAIT()                                                                 \
    do {                                                                         \
        asm volatile("s_waitcnt vmcnt(0)" ::: "memory");                         \
        __builtin_amdgcn_sched_barrier(0);                                       \
    } while (0)

// coherent single-float store (compiler-tracked -> drained before barriers)
union F1U { unsigned u; float f; };
__device__ __forceinline__ void astoref(float* p, float v) {
    F1U c; c.f = v;
    __hip_atomic_store((unsigned*)p, c.u, __ATOMIC_RELAXED, __HIP_MEMORY_SCOPE_AGENT);
}
union F2U { u64 u; float f[2]; };
__device__ __forceinline__ float4 aload4(const float* p) {
    F2U a, b;
    a.u = __hip_atomic_load((const u64*)p,     __ATOMIC_RELAXED, __HIP_MEMORY_SCOPE_AGENT);
    b.u = __hip_atomic_load((const u64*)p + 1, __ATOMIC_RELAXED, __HIP_MEMORY_SCOPE_AGENT);
    return make_float4(a.f[0], a.f[1], b.f[0], b.f[1]);
}

// global poll (tid0 only; <=16 pollers per line by construction)
__device__ __forceinline__ void wait_ge(unsigned* p, unsigned tgt) {
    while (__hip_atomic_load(p, __ATOMIC_RELAXED, __HIP_MEMORY_SCOPE_AGENT) < tgt)
        __builtin_amdgcn_s_sleep(1);
    asm volatile("" ::: "memory");
}

// LDS epoch spin (direct shared-array access; no generic pointer — gfx950 isel bug)
#define LDS_SPIN(idx, tgt)                                                      \
    do {                                                                        \
        while (__hip_atomic_load(&s_done[idx], __ATOMIC_RELAXED,                \
                                 __HIP_MEMORY_SCOPE_WORKGROUP) < (tgt))         \
            __builtin_amdgcn_s_sleep(1);                                        \
        asm volatile("" ::: "memory");                                          \
    } while (0)

#define LDS_POST(idx, val)                                                      \
    __hip_atomic_store(&s_done[idx], (int)(val), __ATOMIC_RELAXED,              \
                       __HIP_MEMORY_SCOPE_WORKGROUP)

// ---------------- precompute kernels (unchanged) ----------------

__global__ void __launch_bounds__(1024) build_decin(const float* __restrict__ mels,
                                                    float* __restrict__ decin) {
    int idx = blockIdx.x * 1024 + threadIdx.x;  // 128*16*80 = 163840
    if (idx >= 128 * 16 * 80) return;
    int t = idx / 1280, r = idx % 1280;
    int b = r / 80, m = r % 80;
    decin[idx] = (t == 0) ? 0.f : mels[b * (80 * 128) + m * 128 + (t - 1)];
}

__global__ void __launch_bounds__(256) gemm_kernel(
    const float* __restrict__ A, int lda,
    const float* __restrict__ B, int ldb,
    float* __restrict__ C, int ldc,
    int M, int N, int K,
    const float* __restrict__ bias1, const float* __restrict__ bias2, int relu) {
    __shared__ float As[16][68];
    __shared__ float Bs[16][68];
    int tid = threadIdx.x;
    int tn = tid & 15, tm = tid >> 4;
    int m0 = blockIdx.y * 64, n0 = blockIdx.x * 64;
    float acc[4][4] = {};
    for (int k0 = 0; k0 < K; k0 += 16) {
        for (int idx = tid; idx < 1024; idx += 256) {
            int mm = idx >> 4, kk = idx & 15;
            int kg = k0 + kk;
            As[kk][mm] = (kg < K) ? A[(size_t)(m0 + mm) * lda + kg] : 0.f;
            Bs[kk][mm] = (kg < K) ? B[(size_t)(n0 + mm) * ldb + kg] : 0.f;
        }
        __syncthreads();
#pragma unroll
        for (int kk = 0; kk < 16; kk++) {
            float av[4], bv[4];
#pragma unroll
            for (int i = 0; i < 4; i++) { av[i] = As[kk][tm * 4 + i]; bv[i] = Bs[kk][tn * 4 + i]; }
#pragma unroll
            for (int i = 0; i < 4; i++)
#pragma unroll
                for (int j = 0; j < 4; j++) acc[i][j] += av[i] * bv[j];
        }
        __syncthreads();
    }
    for (int i = 0; i < 4; i++) {
        int m = m0 + tm * 4 + i;
        for (int j = 0; j < 4; j++) {
            int n = n0 + tn * 4 + j;
            float v = acc[i][j];
            if (bias1) v += bias1[n];
            if (bias2) v += bias2[n];
            if (relu) v = fmaxf(v, 0.f);
            C[(size_t)m * ldc + n] = v;
        }
    }
}

// ---------------- main persistent cooperative kernel ----------------

struct DecArgs {
    const float* memory;
    const int* memlen;
    const float* arnn_wih;
    const float* arnn_whh;
    const float* drnn_wih;
    const float* drnn_whh;
    const float* drnn_bih;
    const float* drnn_bhh;
    const float* query_w;
    const float* v_w;
    const float* conv_w;
    const float* dense_w;
    const float* proj_w;
    const float* proj_b;
    const float* gate_w;
    const float* gate_b;
    float* ws;
    float* out;
};

// waves_per_eu(2,2): VGPR cap 256/wave at the occupancy the 120-KB LDS already
// enforces (1 block/CU = 2 waves/SIMD).
__global__ void __attribute__((amdgpu_flat_work_group_size(512, 512),
                               amdgpu_waves_per_eu(2, 2)))
decoder_main(DecArgs A) {
    cg::grid_group grid = cg::this_grid();
    const int tid = threadIdx.x;
    const int wv = tid >> 6;
    const int l = tid & 63;
    const int blk = blockIdx.x;
    const int u = wv & 3;          // unit within block's 4
    const int kq = wv >> 2;        // K-half {0,1}
    const int jj = blk * 4 + u;    // global hidden-unit id
    const int col = kq * 256 + l * 4;  // column within a 512-wide channel
    float* ws = A.ws;
    unsigned* ctrA = (unsigned*)(ws + OFF_CTR);        // master: 16 adds/step
    unsigned* ctrB = (unsigned*)(ws + OFF_CTR + 32);   // 16 adds/step
    const int grp = blk >> 4;
    unsigned* subA   = (unsigned*)(ws + OFF_CTR + 64 + grp * 32);
    unsigned* bcastA = (unsigned*)(ws + OFF_CTR + 576);   // +idx*32
    unsigned* bcastB = (unsigned*)(ws + OFF_CTR + 1088);  // +idx*32

    // LDS (~123 KB, 1 block/CU)
    __shared__ float s_pm[128 * 132];   // processed memory, padded (attn blocks)
    __shared__ float s_loc[128 * 33];
    __shared__ float s_dw[128 * 33];    // dense_w padded, persistent
    __shared__ float s_cw[1984];        // conv_w persistent (attn blocks)
    __shared__ float s_ah[1024];
    __shared__ float s_ep[512];
    __shared__ float s_part[8][64];     // LSTM partials [wave][b*4+gate]
    __shared__ float s_pp[8][64];       // dec partial (h_a,h_d channels)
    __shared__ float s_pq[128];
    __shared__ float s_aw2[128];
    __shared__ float s_awl[128];        // persistent aw state (attn blocks)
    __shared__ float s_awcl[128];       // persistent cumulative aw
    __shared__ float s_attnc[64];       // persistent attn LSTM c, [eu*16+eb]
    __shared__ float s_decc[64];        // persistent dec  LSTM c
    __shared__ float s_db[16];          // dec biases [u*4+g]
    __shared__ float s_vw[128];
    __shared__ float s_red[2];
    __shared__ int   s_done[2];         // LDS epoch mirrors of the two hops

    // ---- init: zero recurrent state + counters (ws poisoned before each call) ----
    {
        int g = blk * 512 + tid;
        if (g < STATE_FLOATS) ws[OFF_ATTNH + g] = 0.f;
    }
    if (tid < 2) s_done[tid] = 0;
    if (tid < 128) { s_awl[tid] = 0.f; s_awcl[tid] = 0.f; }
    if (tid < 64) { s_attnc[tid] = 0.f; s_decc[tid] = 0.f; }
    if (tid < 16) {
        int uu = tid >> 2, gg = tid & 3;
        s_db[tid] = A.drnn_bih[gg * 1024 + blk * 4 + uu] + A.drnn_bhh[gg * 1024 + blk * 4 + uu];
    }
    if (tid < 128) s_vw[tid] = A.v_w[tid];
    for (int idx = tid; idx < 4096; idx += 512) {
        int a = idx >> 5, f = idx & 31;
        s_dw[a * 33 + f] = A.dense_w[idx];
    }
    if (blk < 16) {
        for (int idx = tid; idx < 16384; idx += 512) {
            int tt = idx >> 7, a = idx & 127;
            s_pm[tt * 132 + a] = ws[OFF_PM + (blk * 128 + tt) * 128 + a];
        }
        for (int idx = tid; idx < 1984; idx += 512) s_cw[idx] = A.conv_w[idx];
    }
    const int ml = (blk < 16) ? A.memlen[blk] : 0;

    // ---- persistent weight registers: loaded via asm (non-rematerializable;
    // the compiler MUST keep these 128 VGPRs live for the whole kernel) ----
    vf4 wA[12];  // attn LSTM [ch*4+g], ch: ctx, h0, h1
#pragma unroll
    for (int g = 0; g < 4; g++)
        wA[g] = gload4(A.arnn_wih + (size_t)(g * 1024 + jj) * 768 + 256 + col);
#pragma unroll
    for (int ch = 1; ch < 3; ch++)
#pragma unroll
        for (int g = 0; g < 4; g++)
            wA[ch * 4 + g] = gload4(A.arnn_whh + (size_t)(g * 1024 + jj) * 1024 + (ch - 1) * 512 + col);
    vf4 wD[20];  // dec LSTM ch: ha0, ha1, ctx, hd0, hd1
#pragma unroll
    for (int ch = 0; ch < 3; ch++)
#pragma unroll
        for (int g = 0; g < 4; g++)
            wD[ch * 4 + g] = gload4(A.drnn_wih + (size_t)(g * 1024 + jj) * 1536 + ch * 512 + col);
#pragma unroll
    for (int ch = 3; ch < 5; ch++)
#pragma unroll
        for (int g = 0; g < 4; g++)
            wD[ch * 4 + g] = gload4(A.drnn_whh + (size_t)(g * 1024 + jj) * 1024 + (ch - 3) * 512 + col);
    VMWAIT();
    __syncthreads();
    grid.sync();   // single cg barrier: init (incl. counters/broadcast) visible

    // packed butterfly: 4 gate-partials over 64 lanes -> lane l holds gate (l&3)
    auto reduce4 = [&](float p0, float p1, float p2, float p3) -> float {
        float a01 = (l & 1) ? p1 : p0;
        float b01 = (l & 1) ? p0 : p1;
        a01 += __shfl_xor(b01, 1);
        float a23 = (l & 1) ? p3 : p2;
        float b23 = (l & 1) ? p2 : p3;
        a23 += __shfl_xor(b23, 1);
        float k_ = (l & 2) ? a23 : a01;
        float s_ = (l & 2) ? a01 : a23;
        k_ += __shfl_xor(s_, 2);
        k_ += __shfl_xor(k_, 4);
        k_ += __shfl_xor(k_, 8);
        k_ += __shfl_xor(k_, 16);
        k_ += __shfl_xor(k_, 32);
        return k_;
    };

    auto attn_stage = [&](int t, int wpar, int rpar) {
        const float* hb = ws + OFF_ATTNH + rpar * 16384;
        const float* cb = ws + OFF_CTX + rpar * 8192;
        float xa0 = 0.f, xa1 = 0.f, xa2 = 0.f, xa3 = 0.f;
        if (tid < 64) {
            int eb = tid & 15, eu = tid >> 4;
            const float* xa = ws + OFF_XA + (size_t)(t * 16 + eb) * 4096 + (blk * 4 + eu);
            xa0 = xa[0]; xa1 = xa[1024]; xa2 = xa[2048]; xa3 = xa[3072];
        }
#pragma unroll
        for (int c = 0; c < 8; c++) {   // 2-batch groups (6 bufs) to cap pressure
            vf4 x[6];
#pragma unroll
            for (int bl = 0; bl < 2; bl++) {
                int b = c * 2 + bl;
                x[bl * 3 + 0] = gload4(cb + b * 512 + col);
                x[bl * 3 + 1] = gload4(hb + b * 1024 + col);
                x[bl * 3 + 2] = gload4(hb + b * 1024 + 512 + col);
            }
            VMWAIT();
#pragma unroll
            for (int bl = 0; bl < 2; bl++) {
                int b = c * 2 + bl;
                float p0 = dotvv(wA[0], x[bl*3]) + dotvv(wA[4], x[bl*3+1]) + dotvv(wA[8],  x[bl*3+2]);
                float p1 = dotvv(wA[1], x[bl*3]) + dotvv(wA[5], x[bl*3+1]) + dotvv(wA[9],  x[bl*3+2]);
                float p2 = dotvv(wA[2], x[bl*3]) + dotvv(wA[6], x[bl*3+1]) + dotvv(wA[10], x[bl*3+2]);
                float p3 = dotvv(wA[3], x[bl*3]) + dotvv(wA[7], x[bl*3+1]) + dotvv(wA[11], x[bl*3+2]);
                float r = reduce4(p0, p1, p2, p3);
                if (l < 4) s_part[wv][b * 4 + l] = r;
            }
        }
        __syncthreads();
        if (tid < 64) {
            int eu = tid >> 4, eb = tid & 15;
            float G0 = s_part[eu][eb * 4 + 0] + s_part[eu + 4][eb * 4 + 0] + xa0;
            float G1 = s_part[eu][eb * 4 + 1] + s_part[eu + 4][eb * 4 + 1] + xa1;
            float G2 = s_part[eu][eb * 4 + 2] + s_part[eu + 4][eb * 4 + 2] + xa2;
            float G3 = s_part[eu][eb * 4 + 3] + s_part[eu + 4][eb * 4 + 3] + xa3;
            float ig = sigmf(G0), fg = sigmf(G1), gg = tanhfast(G2), og = sigmf(G3);
            float c = fg * s_attnc[tid] + ig * gg;
            s_attnc[tid] = c;
            astoref(ws + OFF_ATTNH + wpar * 16384 + eb * 1024 + blk * 4 + eu, og * tanhfast(c));
        }
    };

    auto dec_partial = [&](int wpar, int rpar) {
        const float* hb = ws + OFF_ATTNH + wpar * 16384;
        const float* db = ws + OFF_DECH + rpar * 16384;
#pragma unroll
        for (int c = 0; c < 8; c++) {   // 2-batch groups: 8 loads in flight
            vf4 x[8];
#pragma unroll
            for (int bl = 0; bl < 2; bl++) {
                int b = c * 2 + bl;
                x[bl * 4 + 0] = gload4(hb + b * 1024 + col);
                x[bl * 4 + 1] = gload4(hb + b * 1024 + 512 + col);
                x[bl * 4 + 2] = gload4(db + b * 1024 + col);
                x[bl * 4 + 3] = gload4(db + b * 1024 + 512 + col);
            }
            VMWAIT();
#pragma unroll
            for (int bl = 0; bl < 2; bl++) {
                int b = c * 2 + bl;
                float p0 = dotvv(wD[0], x[bl*4]) + dotvv(wD[4], x[bl*4+1]) + dotvv(wD[12], x[bl*4+2]) + dotvv(wD[16], x[bl*4+3]);
                float p1 = dotvv(wD[1], x[bl*4]) + dotvv(wD[5], x[bl*4+1]) + dotvv(wD[13], x[bl*4+2]) + dotvv(wD[17], x[bl*4+3]);
                float p2 = dotvv(wD[2], x[bl*4]) + dotvv(wD[6], x[bl*4+1]) + dotvv(wD[14], x[bl*4+2]) + dotvv(wD[18], x[bl*4+3]);
                float p3 = dotvv(wD[3], x[bl*4]) + dotvv(wD[7], x[bl*4+1]) + dotvv(wD[15], x[bl*4+2]) + dotvv(wD[19], x[bl*4+3]);
                float r = reduce4(p0, p1, p2, p3);
                if (l < 4) s_pp[wv][b * 4 + l] = r;
            }
        }
    };

    auto dec_tail = [&](int wpar) {
        const float* cb = ws + OFF_CTX + wpar * 8192;
#pragma unroll
        for (int c = 0; c < 2; c++) {
            vf4 xc[8];
#pragma unroll
            for (int bl = 0; bl < 8; bl++) xc[bl] = gload4(cb + (c * 8 + bl) * 512 + col);
            VMWAIT();
#pragma unroll
            for (int bl = 0; bl < 8; bl++) {
                int b = c * 8 + bl;
                float p0 = dotvv(wD[8], xc[bl]);
                float p1 = dotvv(wD[9], xc[bl]);
                float p2 = dotvv(wD[10], xc[bl]);
                float p3 = dotvv(wD[11], xc[bl]);
                float r = reduce4(p0, p1, p2, p3);
                if (l < 4) s_part[wv][b * 4 + l] = r;
            }
        }
        __syncthreads();
        if (tid < 64) {
            int eu = tid >> 4, eb = tid & 15;
            float G0 = s_part[eu][eb * 4 + 0] + s_part[eu + 4][eb * 4 + 0]
                     + s_pp[eu][eb * 4 + 0] + s_pp[eu + 4][eb * 4 + 0] + s_db[eu * 4 + 0];
            float G1 = s_part[eu][eb * 4 + 1] + s_part[eu + 4][eb * 4 + 1]
                     + s_pp[eu][eb * 4 + 1] + s_pp[eu + 4][eb * 4 + 1] + s_db[eu * 4 + 1];
            float G2 = s_part[eu][eb * 4 + 2] + s_part[eu + 4][eb * 4 + 2]
                     + s_pp[eu][eb * 4 + 2] + s_pp[eu + 4][eb * 4 + 2] + s_db[eu * 4 + 2];
            float G3 = s_part[eu][eb * 4 + 3] + s_part[eu + 4][eb * 4 + 3]
                     + s_pp[eu][eb * 4 + 3] + s_pp[eu + 4][eb * 4 + 3] + s_db[eu * 4 + 3];
            float ig = sigmf(G0), fg = sigmf(G1), gg = tanhfast(G2), og = sigmf(G3);
            float c = fg * s_decc[tid] + ig * gg;
            s_decc[tid] = c;
            astoref(ws + OFF_DECH + wpar * 16384 + eb * 1024 + blk * 4 + eu, og * tanhfast(c));
        }
        __syncthreads();  // protect s_part/s_pp against next step's writes
    };

    // location conv: LDS-only, depends on aw(t-1) -> runs BEFORE the A-wait
    auto loc_conv = [&]() {
        for (int idx = tid; idx < 4096; idx += 512) {
            int f = idx >> 7, tt = idx & 127;
            const float* w0 = s_cw + f * 62;
            float s = 0.f;
#pragma unroll
            for (int k = 0; k < 31; k++) {
                int j = tt + k - 15;
                if (j >= 0 && j < 128) s += w0[k] * s_awl[j] + w0[31 + k] * s_awcl[j];
            }
            s_loc[tt * 33 + f] = s;
        }
    };

    auto attention_rest = [&](int t, int wpar) {
        const int b = blk;
        if (tid < 256)
            *(float4*)(s_ah + tid * 4) =
                aload4(ws + OFF_ATTNH + wpar * 16384 + b * 1024 + tid * 4);
        __syncthreads();
        // query projection pq = h @ query_w^T (L2-cached weights)
#pragma unroll 4
        for (int ii = 0; ii < 16; ii++) {
            int a = wv * 16 + ii;
            const float* qw = A.query_w + a * 1024;
            float s = 0.f;
#pragma unroll
            for (int q = 0; q < 4; q++) {
                int k = q * 256 + l * 4;
                float4 h4 = *reinterpret_cast<const float4*>(&s_ah[k]);
                float4 w4 = *reinterpret_cast<const float4*>(&qw[k]);
                s += dot4f(w4, h4);
            }
#pragma unroll
            for (int off = 1; off < 64; off <<= 1) s += __shfl_xor(s, off);
            if (l == 0) s_pq[a] = s;
        }
        __syncthreads();
        // energies
        {
            int tt = tid >> 2, sl = tid & 3;
            float part = 0.f;
            for (int i = 0; i < 32; i++) {
                int a = i * 4 + sl;
                float lp = 0.f;
#pragma unroll
                for (int f = 0; f < 32; f++) lp += s_loc[tt * 33 + f] * s_dw[a * 33 + f];
                float arg = s_pq[a] + lp + s_pm[tt * 132 + a];
                part += s_vw[a] * tanhfast(arg);
            }
            s_ep[tid] = part;
        }
        __syncthreads();
        // row-sum + mask + exp (no max-subtraction: |e| bounded ~11, fp32-safe)
        if (tid < 128) {
            float s = s_ep[tid * 4] + s_ep[tid * 4 + 1] + s_ep[tid * 4 + 2] + s_ep[tid * 4 + 3];
            s_aw2[tid] = (tid >= ml) ? 0.f : __expf(s);
        }
        __syncthreads();
        if (wv == 0) {
            float s = s_aw2[l] + s_aw2[l + 64];
#pragma unroll
            for (int off = 1; off < 64; off <<= 1) s += __shfl_xor(s, off);
            if (l == 0) s_red[0] = 1.f / s;
        }
        __syncthreads();
        if (tid < 128) {
            float val = s_aw2[tid] * s_red[0];
            s_aw2[tid] = val;
            s_awl[tid] = val;          // persistent state for t+1
            s_awcl[tid] += val;
            A.out[165888 + b * 16384 + t * 128 + tid] = val;  // alignments
        }
        __syncthreads();
        // context: ctx[e] = sum_t aw2[t] * memory[b][t][e]  (memory L2-cached)
        {
            const float* mb = A.memory + (size_t)b * 65536 + tid;
            float acc = 0.f;
#pragma unroll 8
            for (int tt2 = 0; tt2 < 128; tt2++) acc += s_aw2[tt2] * mb[tt2 * 512];
            astoref(ws + OFF_CTX + wpar * 8192 + b * 512 + tid, acc);
        }
    };

    auto eout = [&](int tdone) {
        int widx = (blk - 16) * 8 + wv;
        if (widx >= 1296) return;
        int ppar = tdone & 1;
        int b; const float* wrow; float bias; float* dst;
        if (widx < 1280) {
            b = widx / 80; int m = widx % 80;
            wrow = A.proj_w + m * 1536; bias = A.proj_b[m];
            dst = A.out + (size_t)(b * 80 + m) * 128 + tdone;
        } else {
            b = widx - 1280;
            wrow = A.gate_w; bias = A.gate_b[0];
            dst = A.out + 163840 + b * 128 + tdone;
        }
        const float* h1p = ws + OFF_DECH + ppar * 16384 + b * 1024;
        const float* c1p = ws + OFF_CTX + ppar * 8192 + b * 512;
        vf4 h4[6];
#pragma unroll
        for (int q = 0; q < 6; q++) {
            int k = q * 256 + l * 4;
            h4[q] = (k < 1024) ? gload4(h1p + k) : gload4(c1p + k - 1024);
        }
        VMWAIT();
        float s = 0.f;
#pragma unroll
        for (int q = 0; q < 6; q++) {
            int k = q * 256 + l * 4;
            const float4* w4 = reinterpret_cast<const float4*>(&wrow[k]);
            s += w4->x * h4[q][0] + w4->y * h4[q][1] + w4->z * h4[q][2] + w4->w * h4[q][3];
        }
#pragma unroll
        for (int off = 1; off < 64; off <<= 1) s += __shfl_xor(s, off);
        if (l == 0) *dst = s + bias;
    };

    for (int t = 0; t < 128; t++) {
        int wpar = t & 1, rpar = wpar ^ 1;
        unsigned tg = (unsigned)(t + 1);
        attn_stage(t, wpar, rpar);
        __syncthreads();                  // all waves' h_a stores drained
        if (tid == 0) {
            asm volatile("s_waitcnt vmcnt(0)" ::: "memory");
            unsigned old = __hip_atomic_fetch_add(subA, 1u, __ATOMIC_RELAXED,
                                                  __HIP_MEMORY_SCOPE_AGENT);
            if (old == 16u * tg - 1u)
                __hip_atomic_fetch_add(ctrA, 1u, __ATOMIC_RELAXED,
                                       __HIP_MEMORY_SCOPE_AGENT);
        }
        if (blk < 16) {
            loc_conv();                   // LDS-only; overlaps other blocks' stage
            __syncthreads();
            if (tid == 0) {
                wait_ge(ctrA, 16u * tg);  // 16 pollers on this line
                __hip_atomic_store(bcastA + blk * 8, tg, __ATOMIC_RELAXED,
                                   __HIP_MEMORY_SCOPE_AGENT);
                LDS_POST(0, tg);
            } else if (wv > 0) LDS_SPIN(0, (int)tg);
            __syncthreads();
            attention_rest(t, wpar);
            __syncthreads();              // ctx stores drained by all waves
            if (tid == 0) {
                asm volatile("s_waitcnt vmcnt(0)" ::: "memory");
                __hip_atomic_fetch_add(ctrB, 1u, __ATOMIC_RELAXED,
                                       __HIP_MEMORY_SCOPE_AGENT);
            }
            dec_partial(wpar, rpar);      // overlaps other attn blocks' ctx
            if (tid == 0) {
                wait_ge(ctrB, 16u * tg);  // 16 pollers
                __hip_atomic_store(bcastB + blk * 8, tg, __ATOMIC_RELAXED,
                                   __HIP_MEMORY_SCOPE_AGENT);
                LDS_POST(1, tg);
            } else if (wv > 0) LDS_SPIN(1, (int)tg);
            __syncthreads();
            dec_tail(wpar);
        } else {
            if (tid == 0) {
                wait_ge(bcastA + grp * 8, tg);   // <=16 pollers on group line
                LDS_POST(0, tg);
            } else if (wv > 0) LDS_SPIN(0, (int)tg);
            __syncthreads();
            if (t >= 1) eout(t - 1);      // overlaps attention(t)
            dec_partial(wpar, rpar);      // overlaps attention(t) + B-hop
            if (tid == 0) {
                wait_ge(bcastB + grp * 8, tg);
                LDS_POST(1, tg);
            } else if (wv > 0) LDS_SPIN(1, (int)tg);
            __syncthreads();
            dec_tail(wpar);
        }
    }
    // final release: h_d(127) drained by dec_tail's barrier
    if (tid == 0) {
        asm volatile("s_waitcnt vmcnt(0)" ::: "memory");
        unsigned old = __hip_atomic_fetch_add(subA, 1u, __ATOMIC_RELAXED,
                                              __HIP_MEMORY_SCOPE_AGENT);
        if (old == 16u * 129u - 1u)
            __hip_atomic_fetch_add(ctrA, 1u, __ATOMIC_RELAXED, __HIP_MEMORY_SCOPE_AGENT);
    }
    if (blk < 16) {
        if (tid == 0) {
            wait_ge(ctrA, 16u * 129u);
            __hip_atomic_store(bcastA + blk * 8, 129u, __ATOMIC_RELAXED,
                               __HIP_MEMORY_SCOPE_AGENT);
        }
    } else {
        if (tid == 0) { wait_ge(bcastA + grp * 8, 129u); LDS_POST(0, 129); }
        else if (wv > 0) LDS_SPIN(0, 129);
        __syncthreads();
        eout(127);
    }
}

// ---------------- launcher ----------------

extern "C" void kernel_launch(void* const* d_in, const int* in_sizes, int n_in,
                              void* d_out, int out_size, void* d_ws, size_t ws_size,
                              hipStream_t stream) {
    (void)in_sizes; (void)n_in; (void)out_size; (void)ws_size;
    const float* memory    = (const float*)d_in[0];
    const float* mels      = (const float*)d_in[1];
    const int*   memlen    = (const int*)d_in[2];
    const float* prenet_w1 = (const float*)d_in[3];
    const float* prenet_w2 = (const float*)d_in[4];
    const float* arnn_wih  = (const float*)d_in[5];
    const float* arnn_whh  = (const float*)d_in[6];
    const float* arnn_bih  = (const float*)d_in[7];
    const float* arnn_bhh  = (const float*)d_in[8];
    const float* query_w   = (const float*)d_in[9];
    const float* memory_w  = (const float*)d_in[10];
    const float* v_w       = (const float*)d_in[11];
    const float* conv_w    = (const float*)d_in[12];
    const float* dense_w   = (const float*)d_in[13];
    const float* drnn_wih  = (const float*)d_in[14];
    const float* drnn_whh  = (const float*)d_in[15];
    const float* drnn_bih  = (const float*)d_in[16];
    const float* drnn_bhh  = (const float*)d_in[17];
    const float* proj_w    = (const float*)d_in[18];
    const float* proj_b    = (const float*)d_in[19];
    const float* gate_w    = (const float*)d_in[20];
    const float* gate_b    = (const float*)d_in[21];
    float* ws = (float*)d_ws;
    float* out = (float*)d_out;

    build_decin<<<dim3(160), dim3(1024), 0, stream>>>(mels, ws + OFF_DECIN);
    // prenet layer 1: [2048,80]@[80,256]^T, relu
    gemm_kernel<<<dim3(4, 32), dim3(256), 0, stream>>>(ws + OFF_DECIN, 80, prenet_w1, 80,
                                                       ws + OFF_H1, 256, 2048, 256, 80,
                                                       nullptr, nullptr, 1);
    // prenet layer 2
    gemm_kernel<<<dim3(4, 32), dim3(256), 0, stream>>>(ws + OFF_H1, 256, prenet_w2, 256,
                                                       ws + OFF_X, 256, 2048, 256, 256,
                                                       nullptr, nullptr, 1);
    // x-part of attention-LSTM gates + both biases
    gemm_kernel<<<dim3(64, 32), dim3(256), 0, stream>>>(ws + OFF_X, 256, arnn_wih, 768,
                                                        ws + OFF_XA, 4096, 2048, 4096, 256,
                                                        arnn_bih, arnn_bhh, 0);
    // processed memory
    gemm_kernel<<<dim3(2, 32), dim3(256), 0, stream>>>(memory, 512, memory_w, 512,
                                                       ws + OFF_PM, 128, 2048, 128, 512,
                                                       nullptr, nullptr, 0);

    DecArgs a;
    a.memory = memory; a.memlen = memlen;
    a.arnn_wih = arnn_wih; a.arnn_whh = arnn_whh;
    a.drnn_wih = drnn_wih; a.drnn_whh = drnn_whh;
    a.drnn_bih = drnn_bih; a.drnn_bhh = drnn_bhh;
    a.query_w = query_w; a.v_w = v_w;
    a.conv_w = conv_w; a.dense_w = dense_w;
    a.proj_w = proj_w; a.proj_b = proj_b;
    a.gate_w = gate_w; a.gate_b = gate_b;
    a.ws = ws; a.out = out;
    void* kargs[] = { &a };
    hipLaunchCooperativeKernel((const void*)decoder_main, dim3(256), dim3(512),
                               kargs, 0, stream);
}

// Round 18
// 10504.812 us; speedup vs baseline: 1.0164x; 1.0014x over previous
//
#include <hip/hip_runtime.h>
#include <hip/hip_cooperative_groups.h>

namespace cg = cooperative_groups;

// Problem constants
#define N_MEL 80
#define ENC   512
#define ARNN  1024
#define PRE   256
#define ADIM  128
#define NFILT 32
#define KS    31
#define BSZ   16
#define TENC  128
#define TDEC  128

// Workspace layout (float offsets)
#define OFF_XA     0u          // [128][16][4096] precomputed x@Wih_x^T + bih + bhh
#define OFF_X      8388608u    // [128][16][256]  prenet out
#define OFF_H1     8912896u    // [128][16][256]  prenet hidden
#define OFF_DECIN  9437184u    // [128][16][80]
#define OFF_PM     9601024u    // [16][128][128]  processed memory
#define OFF_ATTNH  9863168u    // [2][16][1024]
#define OFF_DECH   9895936u    // [2][16][1024]
#define OFF_CTX    9928704u    // [2][16][512]
#define OFF_CTR    9945088u    // master@0 ctrB@32 subA@64+g*32 bcastA@576+g*32 bcastB@1088+g*32
#define STATE_FLOATS 83520     // OFF_ATTNH .. end of counter/broadcast region

typedef unsigned long long u64;
typedef float vf4 __attribute__((ext_vector_type(4)));   // TRUE vector -> VReg_128 in asm

__device__ __forceinline__ float sigmf(float x) { return 1.0f / (1.0f + __expf(-x)); }
__device__ __forceinline__ float tanhfast(float x) { return 1.0f - 2.0f / (__expf(2.0f * x) + 1.0f); }
__device__ __forceinline__ float dot4f(const float4& w, const float4& x) {
    return w.x * x.x + w.y * x.y + w.z * x.z + w.w * x.w;
}
__device__ __forceinline__ float dotvv(const vf4& w, const vf4& x) {
    return w[0] * x[0] + w[1] * x[1] + w[2] * x[2] + w[3] * x[3];
}

// Coherent PIPELINED load: plain global_load, sc0|sc1, vmcnt-only.
__device__ __forceinline__ vf4 gload4(const float* p) {
    vf4 v;
    asm volatile("global_load_dwordx4 %0, %1, off sc0 sc1" : "=&v"(v) : "v"(p));
    return v;
}
// Counted wait: drains all but the newest n in-flight loads, then fences the
// scheduler so dependent compute cannot hoist above it (rule #18 analog).
#define VMWAITN(n)                                                               \
    do {                                                                         \
        asm volatile("s_waitcnt vmcnt(" #n ")" ::: "memory");                    \
        __builtin_amdgcn_sched_barrier(0);                                       \
    } while (0)
#define VMWAIT() VMWAITN(0)

// coherent single-float store (compiler-tracked -> drained before barriers)
union F1U { unsigned u; float f; };
__device__ __forceinline__ void astoref(float* p, float v) {
    F1U c; c.f = v;
    __hip_atomic_store((unsigned*)p, c.u, __ATOMIC_RELAXED, __HIP_MEMORY_SCOPE_AGENT);
}
union F2U { u64 u; float f[2]; };
__device__ __forceinline__ float4 aload4(const float* p) {
    F2U a, b;
    a.u = __hip_atomic_load((const u64*)p,     __ATOMIC_RELAXED, __HIP_MEMORY_SCOPE_AGENT);
    b.u = __hip_atomic_load((const u64*)p + 1, __ATOMIC_RELAXED, __HIP_MEMORY_SCOPE_AGENT);
    return make_float4(a.f[0], a.f[1], b.f[0], b.f[1]);
}

// global poll (tid0 only; <=16 pollers per line by construction)
__device__ __forceinline__ void wait_ge(unsigned* p, unsigned tgt) {
    while (__hip_atomic_load(p, __ATOMIC_RELAXED, __HIP_MEMORY_SCOPE_AGENT) < tgt)
        __builtin_amdgcn_s_sleep(1);
    asm volatile("" ::: "memory");
}

// LDS epoch spin (direct shared-array access; no generic pointer — gfx950 isel bug)
#define LDS_SPIN(idx, tgt)                                                      \
    do {                                                                        \
        while (__hip_atomic_load(&s_done[idx], __ATOMIC_RELAXED,                \
                                 __HIP_MEMORY_SCOPE_WORKGROUP) < (tgt))         \
            __builtin_amdgcn_s_sleep(1);                                        \
        asm volatile("" ::: "memory");                                          \
    } while (0)

#define LDS_POST(idx, val)                                                      \
    __hip_atomic_store(&s_done[idx], (int)(val), __ATOMIC_RELAXED,              \
                       __HIP_MEMORY_SCOPE_WORKGROUP)

// ---------------- precompute kernels (unchanged) ----------------

__global__ void __launch_bounds__(1024) build_decin(const float* __restrict__ mels,
                                                    float* __restrict__ decin) {
    int idx = blockIdx.x * 1024 + threadIdx.x;  // 128*16*80 = 163840
    if (idx >= 128 * 16 * 80) return;
    int t = idx / 1280, r = idx % 1280;
    int b = r / 80, m = r % 80;
    decin[idx] = (t == 0) ? 0.f : mels[b * (80 * 128) + m * 128 + (t - 1)];
}

__global__ void __launch_bounds__(256) gemm_kernel(
    const float* __restrict__ A, int lda,
    const float* __restrict__ B, int ldb,
    float* __restrict__ C, int ldc,
    int M, int N, int K,
    const float* __restrict__ bias1, const float* __restrict__ bias2, int relu) {
    __shared__ float As[16][68];
    __shared__ float Bs[16][68];
    int tid = threadIdx.x;
    int tn = tid & 15, tm = tid >> 4;
    int m0 = blockIdx.y * 64, n0 = blockIdx.x * 64;
    float acc[4][4] = {};
    for (int k0 = 0; k0 < K; k0 += 16) {
        for (int idx = tid; idx < 1024; idx += 256) {
            int mm = idx >> 4, kk = idx & 15;
            int kg = k0 + kk;
            As[kk][mm] = (kg < K) ? A[(size_t)(m0 + mm) * lda + kg] : 0.f;
            Bs[kk][mm] = (kg < K) ? B[(size_t)(n0 + mm) * ldb + kg] : 0.f;
        }
        __syncthreads();
#pragma unroll
        for (int kk = 0; kk < 16; kk++) {
            float av[4], bv[4];
#pragma unroll
            for (int i = 0; i < 4; i++) { av[i] = As[kk][tm * 4 + i]; bv[i] = Bs[kk][tn * 4 + i]; }
#pragma unroll
            for (int i = 0; i < 4; i++)
#pragma unroll
                for (int j = 0; j < 4; j++) acc[i][j] += av[i] * bv[j];
        }
        __syncthreads();
    }
    for (int i = 0; i < 4; i++) {
        int m = m0 + tm * 4 + i;
        for (int j = 0; j < 4; j++) {
            int n = n0 + tn * 4 + j;
            float v = acc[i][j];
            if (bias1) v += bias1[n];
            if (bias2) v += bias2[n];
            if (relu) v = fmaxf(v, 0.f);
            C[(size_t)m * ldc + n] = v;
        }
    }
}

// ---------------- main persistent cooperative kernel ----------------

struct DecArgs {
    const float* memory;
    const int* memlen;
    const float* arnn_wih;
    const float* arnn_whh;
    const float* drnn_wih;
    const float* drnn_whh;
    const float* drnn_bih;
    const float* drnn_bhh;
    const float* query_w;
    const float* v_w;
    const float* conv_w;
    const float* dense_w;
    const float* proj_w;
    const float* proj_b;
    const float* gate_w;
    const float* gate_b;
    float* ws;
    float* out;
};

__global__ void __attribute__((amdgpu_flat_work_group_size(512, 512),
                               amdgpu_waves_per_eu(2, 2)))
decoder_main(DecArgs A) {
    cg::grid_group grid = cg::this_grid();
    const int tid = threadIdx.x;
    const int wv = tid >> 6;
    const int l = tid & 63;
    const int blk = blockIdx.x;
    const int u = wv & 3;          // unit within block's 4
    const int kq = wv >> 2;        // K-half {0,1}
    const int jj = blk * 4 + u;    // global hidden-unit id
    const int col = kq * 256 + l * 4;  // column within a 512-wide channel
    float* ws = A.ws;
    unsigned* ctrA = (unsigned*)(ws + OFF_CTR);        // master: 16 adds/step
    unsigned* ctrB = (unsigned*)(ws + OFF_CTR + 32);   // 16 adds/step
    const int grp = blk >> 4;
    unsigned* subA   = (unsigned*)(ws + OFF_CTR + 64 + grp * 32);
    unsigned* bcastA = (unsigned*)(ws + OFF_CTR + 576);   // +idx*32
    unsigned* bcastB = (unsigned*)(ws + OFF_CTR + 1088);  // +idx*32

    // LDS (~123 KB, 1 block/CU)
    __shared__ float s_pm[128 * 132];   // processed memory, padded (attn blocks)
    __shared__ float s_loc[128 * 33];
    __shared__ float s_dw[128 * 33];    // dense_w padded, persistent
    __shared__ float s_cw[1984];        // conv_w persistent (attn blocks)
    __shared__ float s_ah[1024];
    __shared__ float s_ep[512];
    __shared__ float s_part[8][64];     // LSTM partials [wave][b*4+gate]
    __shared__ float s_pp[8][64];       // dec partial (h_a,h_d channels)
    __shared__ float s_pq[128];
    __shared__ float s_aw2[128];
    __shared__ float s_awl[128];        // persistent aw state (attn blocks)
    __shared__ float s_awcl[128];       // persistent cumulative aw
    __shared__ float s_attnc[64];       // persistent attn LSTM c, [eu*16+eb]
    __shared__ float s_decc[64];        // persistent dec  LSTM c
    __shared__ float s_db[16];          // dec biases [u*4+g]
    __shared__ float s_vw[128];
    __shared__ float s_red[2];
    __shared__ int   s_done[2];         // LDS epoch mirrors of the two hops

    // ---- init: zero recurrent state + counters (ws poisoned before each call) ----
    {
        int g = blk * 512 + tid;
        if (g < STATE_FLOATS) ws[OFF_ATTNH + g] = 0.f;
    }
    if (tid < 2) s_done[tid] = 0;
    if (tid < 128) { s_awl[tid] = 0.f; s_awcl[tid] = 0.f; }
    if (tid < 64) { s_attnc[tid] = 0.f; s_decc[tid] = 0.f; }
    if (tid < 16) {
        int uu = tid >> 2, gg = tid & 3;
        s_db[tid] = A.drnn_bih[gg * 1024 + blk * 4 + uu] + A.drnn_bhh[gg * 1024 + blk * 4 + uu];
    }
    if (tid < 128) s_vw[tid] = A.v_w[tid];
    for (int idx = tid; idx < 4096; idx += 512) {
        int a = idx >> 5, f = idx & 31;
        s_dw[a * 33 + f] = A.dense_w[idx];
    }
    if (blk < 16) {
        for (int idx = tid; idx < 16384; idx += 512) {
            int tt = idx >> 7, a = idx & 127;
            s_pm[tt * 132 + a] = ws[OFF_PM + (blk * 128 + tt) * 128 + a];
        }
        for (int idx = tid; idx < 1984; idx += 512) s_cw[idx] = A.conv_w[idx];
    }
    const int ml = (blk < 16) ? A.memlen[blk] : 0;

    // ---- persistent weight registers (asm loads: non-rematerializable) ----
    vf4 wA[12];  // attn LSTM [ch*4+g], ch: ctx, h0, h1
#pragma unroll
    for (int g = 0; g < 4; g++)
        wA[g] = gload4(A.arnn_wih + (size_t)(g * 1024 + jj) * 768 + 256 + col);
#pragma unroll
    for (int ch = 1; ch < 3; ch++)
#pragma unroll
        for (int g = 0; g < 4; g++)
            wA[ch * 4 + g] = gload4(A.arnn_whh + (size_t)(g * 1024 + jj) * 1024 + (ch - 1) * 512 + col);
    vf4 wD[20];  // dec LSTM ch: ha0, ha1, ctx, hd0, hd1
#pragma unroll
    for (int ch = 0; ch < 3; ch++)
#pragma unroll
        for (int g = 0; g < 4; g++)
            wD[ch * 4 + g] = gload4(A.drnn_wih + (size_t)(g * 1024 + jj) * 1536 + ch * 512 + col);
#pragma unroll
    for (int ch = 3; ch < 5; ch++)
#pragma unroll
        for (int g = 0; g < 4; g++)
            wD[ch * 4 + g] = gload4(A.drnn_whh + (size_t)(g * 1024 + jj) * 1024 + (ch - 3) * 512 + col);
    VMWAIT();
    __syncthreads();
    grid.sync();   // single cg barrier: init (incl. counters/broadcast) visible

    // packed butterfly: 4 gate-partials over 64 lanes -> lane l holds gate (l&3)
    auto reduce4 = [&](float p0, float p1, float p2, float p3) -> float {
        float a01 = (l & 1) ? p1 : p0;
        float b01 = (l & 1) ? p0 : p1;
        a01 += __shfl_xor(b01, 1);
        float a23 = (l & 1) ? p3 : p2;
        float b23 = (l & 1) ? p2 : p3;
        a23 += __shfl_xor(b23, 1);
        float k_ = (l & 2) ? a23 : a01;
        float s_ = (l & 2) ? a01 : a23;
        k_ += __shfl_xor(s_, 2);
        k_ += __shfl_xor(k_, 4);
        k_ += __shfl_xor(k_, 8);
        k_ += __shfl_xor(k_, 16);
        k_ += __shfl_xor(k_, 32);
        return k_;
    };

    // 2-deep counted-vmcnt pipeline (T4 pattern): issue group c+1 BEFORE
    // draining group c; vmcnt(N) counts only the in-flight next group, so
    // group c's compute (incl. the ~280-cycle reduce4 shuffle chains) hides
    // group c+1's L3 latency. Round 13-17's vmcnt(0)-per-group serialized
    // load->drain->compute — that drain was our own pipeline bug.
    auto attn_stage = [&](int t, int wpar, int rpar) {
        const float* hb = ws + OFF_ATTNH + rpar * 16384;
        const float* cb = ws + OFF_CTX + rpar * 8192;
        float xa0 = 0.f, xa1 = 0.f, xa2 = 0.f, xa3 = 0.f;
        if (tid < 64) {
            int eb = tid & 15, eu = tid >> 4;
            const float* xa = ws + OFF_XA + (size_t)(t * 16 + eb) * 4096 + (blk * 4 + eu);
            xa0 = xa[0]; xa1 = xa[1024]; xa2 = xa[2048]; xa3 = xa[3072];
        }
        vf4 xb[2][6];
        // prologue: group 0 (batches 0,1)
#pragma unroll
        for (int bl = 0; bl < 2; bl++) {
            xb[0][bl * 3 + 0] = gload4(cb + bl * 512 + col);
            xb[0][bl * 3 + 1] = gload4(hb + bl * 1024 + col);
            xb[0][bl * 3 + 2] = gload4(hb + bl * 1024 + 512 + col);
        }
#pragma unroll
        for (int c = 0; c < 8; c++) {
            if (c < 7) {
#pragma unroll
                for (int bl = 0; bl < 2; bl++) {
                    int b = (c + 1) * 2 + bl;
                    xb[(c + 1) & 1][bl * 3 + 0] = gload4(cb + b * 512 + col);
                    xb[(c + 1) & 1][bl * 3 + 1] = gload4(hb + b * 1024 + col);
                    xb[(c + 1) & 1][bl * 3 + 2] = gload4(hb + b * 1024 + 512 + col);
                }
                VMWAITN(6);     // group c done; group c+1 (6 loads) in flight
            } else {
                VMWAITN(0);
            }
            const int p = c & 1;
#pragma unroll
            for (int bl = 0; bl < 2; bl++) {
                int b = c * 2 + bl;
                float p0 = dotvv(wA[0], xb[p][bl*3]) + dotvv(wA[4], xb[p][bl*3+1]) + dotvv(wA[8],  xb[p][bl*3+2]);
                float p1 = dotvv(wA[1], xb[p][bl*3]) + dotvv(wA[5], xb[p][bl*3+1]) + dotvv(wA[9],  xb[p][bl*3+2]);
                float p2 = dotvv(wA[2], xb[p][bl*3]) + dotvv(wA[6], xb[p][bl*3+1]) + dotvv(wA[10], xb[p][bl*3+2]);
                float p3 = dotvv(wA[3], xb[p][bl*3]) + dotvv(wA[7], xb[p][bl*3+1]) + dotvv(wA[11], xb[p][bl*3+2]);
                float r = reduce4(p0, p1, p2, p3);
                if (l < 4) s_part[wv][b * 4 + l] = r;
            }
        }
        __syncthreads();
        if (tid < 64) {
            int eu = tid >> 4, eb = tid & 15;
            float G0 = s_part[eu][eb * 4 + 0] + s_part[eu + 4][eb * 4 + 0] + xa0;
            float G1 = s_part[eu][eb * 4 + 1] + s_part[eu + 4][eb * 4 + 1] + xa1;
            float G2 = s_part[eu][eb * 4 + 2] + s_part[eu + 4][eb * 4 + 2] + xa2;
            float G3 = s_part[eu][eb * 4 + 3] + s_part[eu + 4][eb * 4 + 3] + xa3;
            float ig = sigmf(G0), fg = sigmf(G1), gg = tanhfast(G2), og = sigmf(G3);
            float c = fg * s_attnc[tid] + ig * gg;
            s_attnc[tid] = c;
            astoref(ws + OFF_ATTNH + wpar * 16384 + eb * 1024 + blk * 4 + eu, og * tanhfast(c));
        }
    };

    auto dec_partial = [&](int wpar, int rpar) {
        const float* hb = ws + OFF_ATTNH + wpar * 16384;
        const float* db = ws + OFF_DECH + rpar * 16384;
        vf4 xb[2][8];
        // prologue: group 0 (batches 0,1)
#pragma unroll
        for (int bl = 0; bl < 2; bl++) {
            xb[0][bl * 4 + 0] = gload4(hb + bl * 1024 + col);
            xb[0][bl * 4 + 1] = gload4(hb + bl * 1024 + 512 + col);
            xb[0][bl * 4 + 2] = gload4(db + bl * 1024 + col);
            xb[0][bl * 4 + 3] = gload4(db + bl * 1024 + 512 + col);
        }
#pragma unroll
        for (int c = 0; c < 8; c++) {
            if (c < 7) {
#pragma unroll
                for (int bl = 0; bl < 2; bl++) {
                    int b = (c + 1) * 2 + bl;
                    xb[(c + 1) & 1][bl * 4 + 0] = gload4(hb + b * 1024 + col);
                    xb[(c + 1) & 1][bl * 4 + 1] = gload4(hb + b * 1024 + 512 + col);
                    xb[(c + 1) & 1][bl * 4 + 2] = gload4(db + b * 1024 + col);
                    xb[(c + 1) & 1][bl * 4 + 3] = gload4(db + b * 1024 + 512 + col);
                }
                VMWAITN(8);
            } else {
                VMWAITN(0);
            }
            const int p = c & 1;
#pragma unroll
            for (int bl = 0; bl < 2; bl++) {
                int b = c * 2 + bl;
                float p0 = dotvv(wD[0], xb[p][bl*4]) + dotvv(wD[4], xb[p][bl*4+1]) + dotvv(wD[12], xb[p][bl*4+2]) + dotvv(wD[16], xb[p][bl*4+3]);
                float p1 = dotvv(wD[1], xb[p][bl*4]) + dotvv(wD[5], xb[p][bl*4+1]) + dotvv(wD[13], xb[p][bl*4+2]) + dotvv(wD[17], xb[p][bl*4+3]);
                float p2 = dotvv(wD[2], xb[p][bl*4]) + dotvv(wD[6], xb[p][bl*4+1]) + dotvv(wD[14], xb[p][bl*4+2]) + dotvv(wD[18], xb[p][bl*4+3]);
                float p3 = dotvv(wD[3], xb[p][bl*4]) + dotvv(wD[7], xb[p][bl*4+1]) + dotvv(wD[15], xb[p][bl*4+2]) + dotvv(wD[19], xb[p][bl*4+3]);
                float r = reduce4(p0, p1, p2, p3);
                if (l < 4) s_pp[wv][b * 4 + l] = r;
            }
        }
    };

    auto dec_tail = [&](int wpar) {
        const float* cb = ws + OFF_CTX + wpar * 8192;
        vf4 xc0[8], xc1[8];
#pragma unroll
        for (int bl = 0; bl < 8; bl++) xc0[bl] = gload4(cb + bl * 512 + col);
#pragma unroll
        for (int bl = 0; bl < 8; bl++) xc1[bl] = gload4(cb + (8 + bl) * 512 + col);
        VMWAITN(8);     // first 8 done; second 8 in flight under compute
#pragma unroll
        for (int bl = 0; bl < 8; bl++) {
            float p0 = dotvv(wD[8], xc0[bl]);
            float p1 = dotvv(wD[9], xc0[bl]);
            float p2 = dotvv(wD[10], xc0[bl]);
            float p3 = dotvv(wD[11], xc0[bl]);
            float r = reduce4(p0, p1, p2, p3);
            if (l < 4) s_part[wv][bl * 4 + l] = r;
        }
        VMWAITN(0);
#pragma unroll
        for (int bl = 0; bl < 8; bl++) {
            int b = 8 + bl;
            float p0 = dotvv(wD[8], xc1[bl]);
            float p1 = dotvv(wD[9], xc1[bl]);
            float p2 = dotvv(wD[10], xc1[bl]);
            float p3 = dotvv(wD[11], xc1[bl]);
            float r = reduce4(p0, p1, p2, p3);
            if (l < 4) s_part[wv][b * 4 + l] = r;
        }
        __syncthreads();
        if (tid < 64) {
            int eu = tid >> 4, eb = tid & 15;
            float G0 = s_part[eu][eb * 4 + 0] + s_part[eu + 4][eb * 4 + 0]
                     + s_pp[eu][eb * 4 + 0] + s_pp[eu + 4][eb * 4 + 0] + s_db[eu * 4 + 0];
            float G1 = s_part[eu][eb * 4 + 1] + s_part[eu + 4][eb * 4 + 1]
                     + s_pp[eu][eb * 4 + 1] + s_pp[eu + 4][eb * 4 + 1] + s_db[eu * 4 + 1];
            float G2 = s_part[eu][eb * 4 + 2] + s_part[eu + 4][eb * 4 + 2]
                     + s_pp[eu][eb * 4 + 2] + s_pp[eu + 4][eb * 4 + 2] + s_db[eu * 4 + 2];
            float G3 = s_part[eu][eb * 4 + 3] + s_part[eu + 4][eb * 4 + 3]
                     + s_pp[eu][eb * 4 + 3] + s_pp[eu + 4][eb * 4 + 3] + s_db[eu * 4 + 3];
            float ig = sigmf(G0), fg = sigmf(G1), gg = tanhfast(G2), og = sigmf(G3);
            float c = fg * s_decc[tid] + ig * gg;
            s_decc[tid] = c;
            astoref(ws + OFF_DECH + wpar * 16384 + eb * 1024 + blk * 4 + eu, og * tanhfast(c));
        }
        __syncthreads();  // protect s_part/s_pp against next step's writes
    };

    // location conv: LDS-only, depends on aw(t-1) -> runs BEFORE the A-wait
    auto loc_conv = [&]() {
        for (int idx = tid; idx < 4096; idx += 512) {
            int f = idx >> 7, tt = idx & 127;
            const float* w0 = s_cw + f * 62;
            float s = 0.f;
#pragma unroll
            for (int k = 0; k < 31; k++) {
                int j = tt + k - 15;
                if (j >= 0 && j < 128) s += w0[k] * s_awl[j] + w0[31 + k] * s_awcl[j];
            }
            s_loc[tt * 33 + f] = s;
        }
    };

    auto attention_rest = [&](int t, int wpar) {
        const int b = blk;
        if (tid < 256)
            *(float4*)(s_ah + tid * 4) =
                aload4(ws + OFF_ATTNH + wpar * 16384 + b * 1024 + tid * 4);
        __syncthreads();
        // query projection pq = h @ query_w^T (L2-cached weights)
#pragma unroll 4
        for (int ii = 0; ii < 16; ii++) {
            int a = wv * 16 + ii;
            const float* qw = A.query_w + a * 1024;
            float s = 0.f;
#pragma unroll
            for (int q = 0; q < 4; q++) {
                int k = q * 256 + l * 4;
                float4 h4 = *reinterpret_cast<const float4*>(&s_ah[k]);
                float4 w4 = *reinterpret_cast<const float4*>(&qw[k]);
                s += dot4f(w4, h4);
            }
#pragma unroll
            for (int off = 1; off < 64; off <<= 1) s += __shfl_xor(s, off);
            if (l == 0) s_pq[a] = s;
        }
        __syncthreads();
        // energies
        {
            int tt = tid >> 2, sl = tid & 3;
            float part = 0.f;
            for (int i = 0; i < 32; i++) {
                int a = i * 4 + sl;
                float lp = 0.f;
#pragma unroll
                for (int f = 0; f < 32; f++) lp += s_loc[tt * 33 + f] * s_dw[a * 33 + f];
                float arg = s_pq[a] + lp + s_pm[tt * 132 + a];
                part += s_vw[a] * tanhfast(arg);
            }
            s_ep[tid] = part;
        }
        __syncthreads();
        // row-sum + mask + exp (no max-subtraction: |e| bounded ~11, fp32-safe)
        if (tid < 128) {
            float s = s_ep[tid * 4] + s_ep[tid * 4 + 1] + s_ep[tid * 4 + 2] + s_ep[tid * 4 + 3];
            s_aw2[tid] = (tid >= ml) ? 0.f : __expf(s);
        }
        __syncthreads();
        if (wv == 0) {
            float s = s_aw2[l] + s_aw2[l + 64];
#pragma unroll
            for (int off = 1; off < 64; off <<= 1) s += __shfl_xor(s, off);
            if (l == 0) s_red[0] = 1.f / s;
        }
        __syncthreads();
        if (tid < 128) {
            float val = s_aw2[tid] * s_red[0];
            s_aw2[tid] = val;
            s_awl[tid] = val;          // persistent state for t+1
            s_awcl[tid] += val;
            A.out[165888 + b * 16384 + t * 128 + tid] = val;  // alignments
        }
        __syncthreads();
        // context: ctx[e] = sum_t aw2[t] * memory[b][t][e]  (memory L2-cached)
        {
            const float* mb = A.memory + (size_t)b * 65536 + tid;
            float acc = 0.f;
#pragma unroll 8
            for (int tt2 = 0; tt2 < 128; tt2++) acc += s_aw2[tt2] * mb[tt2 * 512];
            astoref(ws + OFF_CTX + wpar * 8192 + b * 512 + tid, acc);
        }
    };

    auto eout = [&](int tdone) {
        int widx = (blk - 16) * 8 + wv;
        if (widx >= 1296) return;
        int ppar = tdone & 1;
        int b; const float* wrow; float bias; float* dst;
        if (widx < 1280) {
            b = widx / 80; int m = widx % 80;
            wrow = A.proj_w + m * 1536; bias = A.proj_b[m];
            dst = A.out + (size_t)(b * 80 + m) * 128 + tdone;
        } else {
            b = widx - 1280;
            wrow = A.gate_w; bias = A.gate_b[0];
            dst = A.out + 163840 + b * 128 + tdone;
        }
        const float* h1p = ws + OFF_DECH + ppar * 16384 + b * 1024;
        const float* c1p = ws + OFF_CTX + ppar * 8192 + b * 512;
        vf4 h4[6];
#pragma unroll
        for (int q = 0; q < 6; q++) {
            int k = q * 256 + l * 4;
            h4[q] = (k < 1024) ? gload4(h1p + k) : gload4(c1p + k - 1024);
        }
        VMWAIT();
        float s = 0.f;
#pragma unroll
        for (int q = 0; q < 6; q++) {
            int k = q * 256 + l * 4;
            const float4* w4 = reinterpret_cast<const float4*>(&wrow[k]);
            s += w4->x * h4[q][0] + w4->y * h4[q][1] + w4->z * h4[q][2] + w4->w * h4[q][3];
        }
#pragma unroll
        for (int off = 1; off < 64; off <<= 1) s += __shfl_xor(s, off);
        if (l == 0) *dst = s + bias;
    };

    for (int t = 0; t < 128; t++) {
        int wpar = t & 1, rpar = wpar ^ 1;
        unsigned tg = (unsigned)(t + 1);
        attn_stage(t, wpar, rpar);
        __syncthreads();                  // all waves' h_a stores drained
        if (tid == 0) {
            asm volatile("s_waitcnt vmcnt(0)" ::: "memory");
            unsigned old = __hip_atomic_fetch_add(subA, 1u, __ATOMIC_RELAXED,
                                                  __HIP_MEMORY_SCOPE_AGENT);
            if (old == 16u * tg - 1u)
                __hip_atomic_fetch_add(ctrA, 1u, __ATOMIC_RELAXED,
                                       __HIP_MEMORY_SCOPE_AGENT);
        }
        if (blk < 16) {
            loc_conv();                   // LDS-only; overlaps other blocks' stage
            __syncthreads();
            if (tid == 0) {
                wait_ge(ctrA, 16u * tg);  // 16 pollers on this line
                __hip_atomic_store(bcastA + blk * 8, tg, __ATOMIC_RELAXED,
                                   __HIP_MEMORY_SCOPE_AGENT);
                LDS_POST(0, tg);
            } else if (wv > 0) LDS_SPIN(0, (int)tg);
            __syncthreads();
            attention_rest(t, wpar);
            __syncthreads();              // ctx stores drained by all waves
            if (tid == 0) {
                asm volatile("s_waitcnt vmcnt(0)" ::: "memory");
                __hip_atomic_fetch_add(ctrB, 1u, __ATOMIC_RELAXED,
                                       __HIP_MEMORY_SCOPE_AGENT);
            }
            dec_partial(wpar, rpar);      // overlaps other attn blocks' ctx
            if (tid == 0) {
                wait_ge(ctrB, 16u * tg);  // 16 pollers
                __hip_atomic_store(bcastB + blk * 8, tg, __ATOMIC_RELAXED,
                                   __HIP_MEMORY_SCOPE_AGENT);
                LDS_POST(1, tg);
            } else if (wv > 0) LDS_SPIN(1, (int)tg);
            __syncthreads();
            dec_tail(wpar);
        } else {
            if (tid == 0) {
                wait_ge(bcastA + grp * 8, tg);   // <=16 pollers on group line
                LDS_POST(0, tg);
            } else if (wv > 0) LDS_SPIN(0, (int)tg);
            __syncthreads();
            if (t >= 1) eout(t - 1);      // overlaps attention(t)
            dec_partial(wpar, rpar);      // overlaps attention(t) + B-hop
            if (tid == 0) {
                wait_ge(bcastB + grp * 8, tg);
                LDS_POST(1, tg);
            } else if (wv > 0) LDS_SPIN(1, (int)tg);
            __syncthreads();
            dec_tail(wpar);
        }
    }
    // final release: h_d(127) drained by dec_tail's barrier
    if (tid == 0) {
        asm volatile("s_waitcnt vmcnt(0)" ::: "memory");
        unsigned old = __hip_atomic_fetch_add(subA, 1u, __ATOMIC_RELAXED,
                                              __HIP_MEMORY_SCOPE_AGENT);
        if (old == 16u * 129u - 1u)
            __hip_atomic_fetch_add(ctrA, 1u, __ATOMIC_RELAXED, __HIP_MEMORY_SCOPE_AGENT);
    }
    if (blk < 16) {
        if (tid == 0) {
            wait_ge(ctrA, 16u * 129u);
            __hip_atomic_store(bcastA + blk * 8, 129u, __ATOMIC_RELAXED,
                               __HIP_MEMORY_SCOPE_AGENT);
        }
    } else {
        if (tid == 0) { wait_ge(bcastA + grp * 8, 129u); LDS_POST(0, 129); }
        else if (wv > 0) LDS_SPIN(0, 129);
        __syncthreads();
        eout(127);
    }
}

// ---------------- launcher ----------------

extern "C" void kernel_launch(void* const* d_in, const int* in_sizes, int n_in,
                              void* d_out, int out_size, void* d_ws, size_t ws_size,
                              hipStream_t stream) {
    (void)in_sizes; (void)n_in; (void)out_size; (void)ws_size;
    const float* memory    = (const float*)d_in[0];
    const float* mels      = (const float*)d_in[1];
    const int*   memlen    = (const int*)d_in[2];
    const float* prenet_w1 = (const float*)d_in[3];
    const float* prenet_w2 = (const float*)d_in[4];
    const float* arnn_wih  = (const float*)d_in[5];
    const float* arnn_whh  = (const float*)d_in[6];
    const float* arnn_bih  = (const float*)d_in[7];
    const float* arnn_bhh  = (const float*)d_in[8];
    const float* query_w   = (const float*)d_in[9];
    const float* memory_w  = (const float*)d_in[10];
    const float* v_w       = (const float*)d_in[11];
    const float* conv_w    = (const float*)d_in[12];
    const float* dense_w   = (const float*)d_in[13];
    const float* drnn_wih  = (const float*)d_in[14];
    const float* drnn_whh  = (const float*)d_in[15];
    const float* drnn_bih  = (const float*)d_in[16];
    const float* drnn_bhh  = (const float*)d_in[17];
    const float* proj_w    = (const float*)d_in[18];
    const float* proj_b    = (const float*)d_in[19];
    const float* gate_w    = (const float*)d_in[20];
    const float* gate_b    = (const float*)d_in[21];
    float* ws = (float*)d_ws;
    float* out = (float*)d_out;

    build_decin<<<dim3(160), dim3(1024), 0, stream>>>(mels, ws + OFF_DECIN);
    // prenet layer 1: [2048,80]@[80,256]^T, relu
    gemm_kernel<<<dim3(4, 32), dim3(256), 0, stream>>>(ws + OFF_DECIN, 80, prenet_w1, 80,
                                                       ws + OFF_H1, 256, 2048, 256, 80,
                                                       nullptr, nullptr, 1);
    // prenet layer 2
    gemm_kernel<<<dim3(4, 32), dim3(256), 0, stream>>>(ws + OFF_H1, 256, prenet_w2, 256,
                                                       ws + OFF_X, 256, 2048, 256, 256,
                                                       nullptr, nullptr, 1);
    // x-part of attention-LSTM gates + both biases
    gemm_kernel<<<dim3(64, 32), dim3(256), 0, stream>>>(ws + OFF_X, 256, arnn_wih, 768,
                                                        ws + OFF_XA, 4096, 2048, 4096, 256,
                                                        arnn_bih, arnn_bhh, 0);
    // processed memory
    gemm_kernel<<<dim3(2, 32), dim3(256), 0, stream>>>(memory, 512, memory_w, 512,
                                                       ws + OFF_PM, 128, 2048, 128, 512,
                                                       nullptr, nullptr, 0);

    DecArgs a;
    a.memory = memory; a.memlen = memlen;
    a.arnn_wih = arnn_wih; a.arnn_whh = arnn_whh;
    a.drnn_wih = drnn_wih; a.drnn_whh = drnn_whh;
    a.drnn_bih = drnn_bih; a.drnn_bhh = drnn_bhh;
    a.query_w = query_w; a.v_w = v_w;
    a.conv_w = conv_w; a.dense_w = dense_w;
    a.proj_w = proj_w; a.proj_b = proj_b;
    a.gate_w = gate_w; a.gate_b = gate_b;
    a.ws = ws; a.out = out;
    void* kargs[] = { &a };
    hipLaunchCooperativeKernel((const void*)decoder_main, dim3(256), dim3(512),
                               kargs, 0, stream);
}